// Round 1
// baseline (992.885 us; speedup 1.0000x reference)
//
#include <hip/hip_runtime.h>
#include <math.h>

typedef unsigned short u16;
typedef __bf16 bf16x8 __attribute__((ext_vector_type(8)));
typedef float   f32x4 __attribute__((ext_vector_type(4)));
typedef u16     u16x4 __attribute__((ext_vector_type(4)));

// ---------- constants ----------
#define TOK 25088      // B*C*H*W
#define EMB 768
#define NWH 1536       // 128 windows * 12 heads
#define NTOKW 196      // tokens per window
#define PROW 224       // padded vT row length (7 * 32)
#define PPAD 232       // LDS P-strip row pitch (16B-aligned, breaks quad bank collision)
#define GROUP_M 4      // m-blocks per L2-locality supertile

// workspace byte offsets (q/k live in d_out)
#define OFF_VT 38535168ull
#define OFF_W0 127565824ull           // wqkvT 3,538,944
#define OFF_W1 131104768ull           // wprojT 1,179,648
#define OFF_W2 132284416ull           // w1T 4,718,592
#define OFF_W3 137003008ull           // w2T 4,718,592 -> end 141,721,600
#define OFF_H  38535168ull            // hb aliases vT+ (77,070,336 for 12544 rows)

__device__ __forceinline__ u16 f2bf(float f) {
  __bf16 h = (__bf16)f;
  return __builtin_bit_cast(u16, h);
}

__device__ __forceinline__ float bf2f(u16 u) {
  return __builtin_bit_cast(float, (unsigned)u << 16);
}

__device__ __forceinline__ void cp16(void* lds, const void* gsrc) {
  // async global->LDS, 16B per lane; LDS dest is wave-uniform base (+lane*16 implicit)
  __builtin_amdgcn_global_load_lds((const __attribute__((address_space(1))) void*)gsrc,
                                   (__attribute__((address_space(3))) void*)lds,
                                   16, 0, 0);
}

__device__ __forceinline__ f32x4 mfma16(bf16x8 a, bf16x8 b, f32x4 c) {
  return __builtin_amdgcn_mfma_f32_16x16x32_bf16(a, b, c, 0, 0, 0);
}

// ---------- weight transpose fp32[R][C] -> bf16[C][R] ----------
__global__ __launch_bounds__(256)
void transpose_w(const float* __restrict__ src, u16* __restrict__ dst, int R, int C) {
  __shared__ float tile[32][33];
  const int tx = threadIdx.x & 31;
  const int ty = threadIdx.x >> 5;
  const int c0 = blockIdx.x * 32;
  const int r0 = blockIdx.y * 32;
  #pragma unroll
  for (int i = ty; i < 32; i += 8)
    tile[i][tx] = src[(size_t)(r0 + i) * C + c0 + tx];
  __syncthreads();
  #pragma unroll
  for (int i = ty; i < 32; i += 8)
    dst[(size_t)(c0 + i) * R + r0 + tx] = f2bf(tile[tx][i]);
}

// ---------- LayerNorm (wave per row) ----------
template<bool WIN>
__global__ __launch_bounds__(256)
void ln_kernel(const float* __restrict__ x, const float* __restrict__ g,
               const float* __restrict__ b, u16* __restrict__ y) {
  const int wave = threadIdx.x >> 6;
  const int lane = threadIdx.x & 63;
  const int row = blockIdx.x * 4 + wave;
  const float* xr = x + (size_t)row * EMB;
  float4 v[3];
  float s = 0.f, ss = 0.f;
  #pragma unroll
  for (int j = 0; j < 3; j++) {
    v[j] = *(const float4*)&xr[lane * 4 + j * 256];
    s  += v[j].x + v[j].y + v[j].z + v[j].w;
    ss += v[j].x*v[j].x + v[j].y*v[j].y + v[j].z*v[j].z + v[j].w*v[j].w;
  }
  #pragma unroll
  for (int off = 1; off < 64; off <<= 1) {
    s  += __shfl_xor(s, off);
    ss += __shfl_xor(ss, off);
  }
  const float mu = s * (1.0f / 768.0f);
  const float var = ss * (1.0f / 768.0f) - mu * mu;
  const float rs = rsqrtf(var + 1e-5f);
  size_t drow;
  if (WIN) {
    const int bc = row / 3136;
    const int rem = row - bc * 3136;
    const int h = rem / 56;
    const int w = rem - h * 56;
    const int window = bc * 16 + (h / 14) * 4 + (w / 14);
    const int token = (h % 14) * 14 + (w % 14);
    drow = (size_t)window * NTOKW + token;
  } else {
    drow = (size_t)row;
  }
  u16* yr = y + drow * EMB;
  #pragma unroll
  for (int j = 0; j < 3; j++) {
    const int e = lane * 4 + j * 256;
    const float4 gv = *(const float4*)&g[e];
    const float4 bv = *(const float4*)&b[e];
    u16x4 o;
    o[0] = f2bf((v[j].x - mu) * rs * gv.x + bv.x);
    o[1] = f2bf((v[j].y - mu) * rs * gv.y + bv.y);
    o[2] = f2bf((v[j].z - mu) * rs * gv.z + bv.z);
    o[3] = f2bf((v[j].w - mu) * rs * gv.w + bv.w);
    *(u16x4*)&yr[e] = o;
  }
}

// ---------- 256x256 8-phase pipelined bf16 GEMM (T2+T3+T4+T5), fused epilogues ----------
// BK=64, 2 K-tiles/iteration, 8 waves (2M x 4N), per-wave C = 128x64.
// LDS: 2 buffers x (A[256][64] + B[256][64]) bf16 = 128 KiB, 1 block/CU.
// XOR swizzle: 16B chunk pc at (row,pc) holds logical chunk pc^(row&7); applied on
// the pre-swizzled GLOBAL source of global_load_lds (dest stays linear) + ds_read addr.
// Stage schedule (tile 2t in buf0 ph1-4, tile 2t+1 in buf1 ph5-8):
//   ph1/2: A(2t+1)->buf1   [buf1.A last read iter t-1 ph8]
//   ph3/4: B(2t+2)->buf0   [buf0.B last read ph1]
//   ph5/6: A(2t+2)->buf0   [buf0.A last read ph4]
//   ph7/8: B(2t+3)->buf1   [buf1.B last read ph5]
// vmcnt(4) at ph4/ph8 boundaries (in-order retirement -> retires exactly the
// needed tile, leaves 2 half-tiles = 4 loads in flight). Never 0 in main loop.
#define EPI_QKV  0
#define EPI_PROJ 1
#define EPI_MLP1 2
#define EPI_MLP2 3

template<int EPI>
__global__ __launch_bounds__(512, 2)
void gemm256(const u16* __restrict__ A, const u16* __restrict__ Bt,
             int K, int moff, int nbm, int nbn,
             const float* __restrict__ bias,
             const float* __restrict__ aux,   // PROJ: x (shortcut); MLP2: x1 (=d_out)
             u16* __restrict__ o0, u16* __restrict__ o1, u16* __restrict__ o2,
             float* of) {
  __shared__ __align__(16) u16 lds[2][2][256 * 64];   // [buf][0=A,1=B][row][64]
  const int t = threadIdx.x;
  const int wave = t >> 6;
  const int lane = t & 63;
  const int quad = lane >> 4;
  const int l16 = lane & 15;
  const int wm = wave >> 2;       // 0..1  (M half)
  const int wn = wave & 3;        // 0..3  (N quarter)

  // L2-locality swizzle: supertile = GROUP_M m-blocks x all n-blocks, n-fast
  const int in_group = GROUP_M * nbn;
  const int gid = blockIdx.x / in_group;
  const int rem0 = blockIdx.x - gid * in_group;
  const int gm = min(GROUP_M, nbm - gid * GROUP_M);
  const int bm = gid * GROUP_M + rem0 % gm;
  const int bn = rem0 / gm;
  const int m0 = bm * 256;
  const int n0 = bn * 256;

  // staging: half-tile = 128 rows x 64 cols, chunk c = round*512 + t;
  // row = c>>3, phys chunk = c&7, logical col chunk = (c ^ (c>>3)) & 7
  const int sr0 = t >> 3;
  const int sc0 = ((t ^ (t >> 3)) & 7) * 8;
  const int c1_ = t + 512;
  const int sr1 = c1_ >> 3;
  const int sc1 = ((c1_ ^ (c1_ >> 3)) & 7) * 8;
  const u16* Ag0 = A + (size_t)(m0 + sr0) * K + sc0;
  const u16* Ag1 = A + (size_t)(m0 + sr1) * K + sc1;
  const u16* Bg0 = Bt + (size_t)(n0 + sr0) * K + sc0;
  const u16* Bg1 = Bt + (size_t)(n0 + sr1) * K + sc1;
  const size_t hstep = (size_t)128 * K;    // half-tile row step in source

  // ds_read swizzled chunk offsets (row&7 == l16&7: all row bases are mult of 16)
  const int cK0 = ((quad    ) ^ (l16 & 7)) * 8;   // ksub 0
  const int cK1 = ((4 + quad) ^ (l16 & 7)) * 8;   // ksub 1

  f32x4 acc[8][4];
  const f32x4 zero4 = {0.f, 0.f, 0.f, 0.f};
  #pragma unroll
  for (int i = 0; i < 8; i++)
    #pragma unroll
    for (int j = 0; j < 4; j++) acc[i][j] = zero4;
  bf16x8 bfr[4][2];

#define STG(bb, mat, half, G0, G1, kk) do {                                          \
    cp16(&lds[bb][mat][(half) * 8192 + wave * 512],        (G0) + (half) * hstep + (kk)); \
    cp16(&lds[bb][mat][(half) * 8192 + 4096 + wave * 512], (G1) + (half) * hstep + (kk)); \
  } while (0)

#define LOADB(bb) do {                                                               \
    _Pragma("unroll")                                                                \
    for (int nf = 0; nf < 4; nf++) {                                                 \
      bfr[nf][0] = *(const bf16x8*)&lds[bb][1][(wn * 64 + nf * 16 + l16) * 64 + cK0];\
      bfr[nf][1] = *(const bf16x8*)&lds[bb][1][(wn * 64 + nf * 16 + l16) * 64 + cK1];\
    }                                                                                \
  } while (0)

#define PHASE(bb, slab, PRE, POST) do {                                              \
    const int ar_ = (wm * 128 + (slab) * 32 + l16) * 64;                             \
    bf16x8 a00 = *(const bf16x8*)&lds[bb][0][ar_ + cK0];                             \
    bf16x8 a01 = *(const bf16x8*)&lds[bb][0][ar_ + cK1];                             \
    bf16x8 a10 = *(const bf16x8*)&lds[bb][0][ar_ + 1024 + cK0];                      \
    bf16x8 a11 = *(const bf16x8*)&lds[bb][0][ar_ + 1024 + cK1];                      \
    PRE;                                                                             \
    __builtin_amdgcn_s_barrier();                                                    \
    asm volatile("s_waitcnt lgkmcnt(0)" ::: "memory");                               \
    __builtin_amdgcn_sched_barrier(0);                                               \
    __builtin_amdgcn_s_setprio(1);                                                   \
    _Pragma("unroll")                                                                \
    for (int nf = 0; nf < 4; nf++) {                                                 \
      acc[(slab) * 2    ][nf] = mfma16(a00, bfr[nf][0], acc[(slab) * 2    ][nf]);    \
      acc[(slab) * 2    ][nf] = mfma16(a01, bfr[nf][1], acc[(slab) * 2    ][nf]);    \
      acc[(slab) * 2 + 1][nf] = mfma16(a10, bfr[nf][0], acc[(slab) * 2 + 1][nf]);    \
      acc[(slab) * 2 + 1][nf] = mfma16(a11, bfr[nf][1], acc[(slab) * 2 + 1][nf]);    \
    }                                                                                \
    __builtin_amdgcn_s_setprio(0);                                                   \
    POST;                                                                            \
    __builtin_amdgcn_s_barrier();                                                    \
  } while (0)

  // prologue: B(0)->buf0, A(0)->buf0, B(1)->buf1  (12 loads in flight)
  STG(0, 1, 0, Bg0, Bg1, 0);  STG(0, 1, 1, Bg0, Bg1, 0);
  STG(0, 0, 0, Ag0, Ag1, 0);  STG(0, 0, 1, Ag0, Ag1, 0);
  STG(1, 1, 0, Bg0, Bg1, 64); STG(1, 1, 1, Bg0, Bg1, 64);
  asm volatile("s_waitcnt vmcnt(4)" ::: "memory");   // tile0 landed; B(1) in flight
  __builtin_amdgcn_s_barrier();

  const int T = K >> 7;       // iterations, 2 K-tiles each (K % 128 == 0)
  for (int it = 0; it < T; ++it) {
    const bool nlast = (it < T - 1);
    const int kA1 = (2 * it + 1) << 6;
    const int kT2 = (2 * it + 2) << 6;
    const int kT3 = (2 * it + 3) << 6;

    LOADB(0);
    PHASE(0, 0, STG(1, 0, 0, Ag0, Ag1, kA1), );
    PHASE(0, 1, STG(1, 0, 1, Ag0, Ag1, kA1), );
    PHASE(0, 2, if (nlast) STG(0, 1, 0, Bg0, Bg1, kT2), );
    PHASE(0, 3, if (nlast) STG(0, 1, 1, Bg0, Bg1, kT2),
          if (nlast) { asm volatile("s_waitcnt vmcnt(4)" ::: "memory"); }
          else       { asm volatile("s_waitcnt vmcnt(0)" ::: "memory"); }
          __builtin_amdgcn_sched_barrier(0); );
    LOADB(1);
    PHASE(1, 0, if (nlast) STG(0, 0, 0, Ag0, Ag1, kT2), );
    PHASE(1, 1, if (nlast) STG(0, 0, 1, Ag0, Ag1, kT2), );
    PHASE(1, 2, if (nlast) STG(1, 1, 0, Bg0, Bg1, kT3), );
    PHASE(1, 3, if (nlast) STG(1, 1, 1, Bg0, Bg1, kT3),
          asm volatile("s_waitcnt vmcnt(4)" ::: "memory");
          __builtin_amdgcn_sched_barrier(0); );
  }
#undef STG
#undef LOADB
#undef PHASE

  // epilogue: lane holds D[row = quad*4+r][col = l16] per 16x16 tile
  #pragma unroll
  for (int mf = 0; mf < 8; mf++) {
    const int mb = m0 + wm * 128 + mf * 16 + quad * 4;
    #pragma unroll
    for (int nf = 0; nf < 4; nf++) {
      const int n = n0 + wn * 64 + nf * 16 + l16;
      const float bn_ = bias[n];
      if (EPI == EPI_QKV) {
        const int j3 = n / 768;
        const int rem = n - j3 * 768;
        const int head = rem >> 6;
        const int d = rem & 63;
        if (j3 == 2) {
          // v stored transposed: vT[wh][d][PROW], 4 consecutive tokens per lane
          const int window = mb / 196;
          const int token = mb - window * 196;   // mb%4==0, 196%4==0 -> same window
          const int wh = window * 12 + head;
          u16x4 pv;
          #pragma unroll
          for (int r = 0; r < 4; r++) pv[r] = f2bf(acc[mf][nf][r] + bn_);
          *(u16x4*)&o2[((size_t)wh * 64 + d) * PROW + token] = pv;
        } else {
          u16* dst = (j3 == 0) ? o0 : o1;
          #pragma unroll
          for (int r = 0; r < 4; r++) {
            const int m = mb + r;
            const int window = m / 196;
            const int token = m - window * 196;
            const int wh = window * 12 + head;
            dst[((size_t)wh * NTOKW + token) * 64 + d] = f2bf(acc[mf][nf][r] + bn_);
          }
        }
      } else if (EPI == EPI_PROJ) {
        #pragma unroll
        for (int r = 0; r < 4; r++) {
          const int m = mb + r;
          const int window = m / 196;
          const int token = m - window * 196;
          const int bc = window >> 4;
          const int wi = window & 15;
          const int th = token / 14;
          const int tw = token - th * 14;
          const int h = (wi >> 2) * 14 + th;
          const int w = (wi & 3) * 14 + tw;
          const size_t flat = (((size_t)bc * 56 + h) * 56 + w) * 768 + n;
          of[flat] = acc[mf][nf][r] + bn_ + aux[flat];   // x1 = proj + bias + shortcut
        }
      } else if (EPI == EPI_MLP1) {
        #pragma unroll
        for (int r = 0; r < 4; r++) {
          const int m = mb + r;
          float v = acc[mf][nf][r] + bn_;
          v = 0.5f * v * (1.0f + erff(v * 0.70710678118654752f));  // exact GELU
          o0[(size_t)m * 3072 + n] = f2bf(v);
        }
      } else {  // EPI_MLP2
        #pragma unroll
        for (int r = 0; r < 4; r++) {
          const int m = mb + r + moff;
          const size_t idx = (size_t)m * 768 + n;
          of[idx] = acc[mf][nf][r] + bn_ + aux[idx];     // out = z + x1
        }
      }
    }
  }
}

// ---------- fused attention: S=scale*qk^T+rel, softmax, O=P@V — one kernel ----------
// lsK XOR-swizzled: physical chunk c of row holds logical c^(row&7) (8 chunks/row).
__global__ __launch_bounds__(256, 2)
void attn_fused(const u16* __restrict__ q, const u16* __restrict__ k,
                const u16* __restrict__ vT,
                const float* __restrict__ rph, const float* __restrict__ rpw,
                u16* __restrict__ out) {
  __shared__ __align__(16) u16 lsK[208 * 64];   // 26624 B (rows 196.. stale; cols masked)
  __shared__ __align__(16) u16 relh[16 * 224];  // bf16 [kh][i]  7168 B
  __shared__ __align__(16) u16 relw[16 * 224];  // bf16 [kw][i]  7168 B
  __shared__ __align__(16) u16 lsP[4][16 * PPAD]; // 29696 B, wave-private strips
  const int t = threadIdx.x;
  const int wave = t >> 6;
  const int lane = t & 63;
  const int quad = lane >> 4;
  const int l16 = lane & 15;
  const int wh = blockIdx.x;
  const u16* qg = q + (size_t)wh * (NTOKW * 64);
  const u16* kg = k + (size_t)wh * (NTOKW * 64);
  const u16* vg = vT + (size_t)wh * 64 * PROW;
  const int window = wh / 12;
  const int head = wh - window * 12;

  // stage k rows 0..195 with XOR source swizzle (chunk c of row r <- logical c^(r&7))
  #pragma unroll
  for (int i = 0; i < 6; i++) {
    const int chunk = i * 256 + t;
    const int goff = ((chunk & ~7) | ((chunk ^ (chunk >> 3)) & 7)) * 8;
    cp16(lsK + (i * 256 + wave * 64) * 8, kg + goff);
  }
  if (t < 32) {
    const int chunk = 1536 + t;
    const int goff = ((chunk & ~7) | ((chunk ^ (chunk >> 3)) & 7)) * 8;
    cp16(lsK + 1536 * 8, kg + goff);
  }

  // rel_h / rel_w tables via MFMA (bf16 in LDS)
  const f32x4 zero4 = {0.f, 0.f, 0.f, 0.f};
  for (int tile = wave; tile < 14; tile += 4) {
    f32x4 ah = zero4, aw = zero4;
    const int ridx = min(max(tile - l16 + 13, 0), 26);  // clamp (l16>=14 cols discarded)
    #pragma unroll
    for (int ks = 0; ks < 2; ks++) {
      const int ko = ks * 32 + quad * 8;
      bf16x8 aq_h = *(const bf16x8*)&qg[(tile * 14 + l16) * 64 + ko];
      bf16x8 aq_w = *(const bf16x8*)&qg[(tile + 14 * l16) * 64 + ko];
      bf16x8 bh, bw;
      const float* ph = rph + ridx * 64 + ko;
      const float* pw = rpw + ridx * 64 + ko;
      #pragma unroll
      for (int e = 0; e < 8; e++) { bh[e] = (__bf16)ph[e]; bw[e] = (__bf16)pw[e]; }
      ah = mfma16(aq_h, bh, ah);
      aw = mfma16(aq_w, bw, aw);
    }
    #pragma unroll
    for (int r = 0; r < 4; r++) {
      const int m = quad * 4 + r;
      if (m < 14) {
        relh[l16 * 224 + tile * 14 + m] = f2bf(ah[r]);
        relw[l16 * 224 + tile + 14 * m] = f2bf(aw[r]);
      }
    }
  }
  __syncthreads();   // drains cp16 vmcnt + publishes rel tables

  const float scale = 0.125f;  // 64^-0.5
  const int sw = l16 & 7;      // lsK read swizzle (row&7 == l16&7 for rows = jt*16+l16)
  u16* myP = &lsP[wave][0];
  for (int s = wave; s < 13; s += 4) {
    bf16x8 aq[2];
    #pragma unroll
    for (int ks = 0; ks < 2; ks++)
      aq[ks] = *(const bf16x8*)&qg[(s * 16 + l16) * 64 + ks * 32 + quad * 8];
    f32x4 acc[13];
    #pragma unroll
    for (int jt = 0; jt < 13; jt++) {
      f32x4 a = zero4;
      a = mfma16(aq[0], *(const bf16x8*)&lsK[(jt * 16 + l16) * 64 + (quad ^ sw) * 8], a);
      a = mfma16(aq[1], *(const bf16x8*)&lsK[(jt * 16 + l16) * 64 + ((quad + 4) ^ sw) * 8], a);
      acc[jt] = a;
    }
    f32x4 mx = {-1e30f, -1e30f, -1e30f, -1e30f};
    #pragma unroll
    for (int jt = 0; jt < 13; jt++) {
      const int col = jt * 16 + l16;
      if (col < 196) {
        const int kh = col / 14;
        const int kw = col - kh * 14;
        const u16x4 rhu = *(const u16x4*)&relh[kh * 224 + s * 16 + quad * 4];
        const u16x4 rwu = *(const u16x4*)&relw[kw * 224 + s * 16 + quad * 4];
        #pragma unroll
        for (int r = 0; r < 4; r++)
          acc[jt][r] = acc[jt][r] * scale + bf2f(rhu[r]) + bf2f(rwu[r]);
      } else {
        acc[jt] = (f32x4){-1e30f, -1e30f, -1e30f, -1e30f};  // full overwrite: kills stale LDS
      }
      #pragma unroll
      for (int r = 0; r < 4; r++) mx[r] = fmaxf(mx[r], acc[jt][r]);
    }
    // rows live per-quad (xor masks <16 stay inside the 16-lane group)
    #pragma unroll
    for (int off = 1; off < 16; off <<= 1)
      #pragma unroll
      for (int r = 0; r < 4; r++) mx[r] = fmaxf(mx[r], __shfl_xor(mx[r], off));
    f32x4 sum = zero4;
    #pragma unroll
    for (int jt = 0; jt < 13; jt++)
      #pragma unroll
      for (int r = 0; r < 4; r++) {
        const float p = exp2f((acc[jt][r] - mx[r]) * 1.4426950408889634f);
        acc[jt][r] = p;
        sum[r] += p;
      }
    #pragma unroll
    for (int off = 1; off < 16; off <<= 1)
      #pragma unroll
      for (int r = 0; r < 4; r++) sum[r] += __shfl_xor(sum[r], off);
    // write P strip (wave-private; rows = quad*4+r, cols = jt*16+l16)
    #pragma unroll
    for (int r = 0; r < 4; r++) {
      const float rinv = 1.0f / sum[r];
      const int prow = (quad * 4 + r) * PPAD;
      #pragma unroll
      for (int jt = 0; jt < 13; jt++)
        myP[prow + jt * 16 + l16] = f2bf(acc[jt][r] * rinv);
      myP[prow + 208 + l16] = 0;   // zero pad cols 208..223
    }
    asm volatile("s_waitcnt lgkmcnt(0)" ::: "memory");  // P strip visible to own wave
    // O = P @ V ; A-frag from LDS strip, B-frag (vT) from global (L1/L2-resident)
    f32x4 acco[4] = {zero4, zero4, zero4, zero4};
    #pragma unroll
    for (int ks = 0; ks < 7; ks++) {
      bf16x8 ap = *(const bf16x8*)&myP[l16 * PPAD + ks * 32 + quad * 8];
      #pragma unroll
      for (int nt = 0; nt < 4; nt++) {
        bf16x8 bv = *(const bf16x8*)&vg[(nt * 16 + l16) * PROW + ks * 32 + quad * 8];
        acco[nt] = mfma16(ap, bv, acco[nt]);
      }
    }
    #pragma unroll
    for (int nt = 0; nt < 4; nt++)
      #pragma unroll
      for (int r = 0; r < 4; r++) {
        const int i = s * 16 + quad * 4 + r;
        if (i < 196)
          out[((size_t)window * NTOKW + i) * EMB + head * 64 + nt * 16 + l16] =
              f2bf(acco[nt][r]);
      }
  }
}

// ---------- launch ----------
extern "C" void kernel_launch(void* const* d_in, const int* in_sizes, int n_in,
                              void* d_out, int out_size, void* d_ws, size_t ws_size,
                              hipStream_t stream) {
  const float* x      = (const float*)d_in[0];
  const float* n1w    = (const float*)d_in[1];
  const float* n1b    = (const float*)d_in[2];
  const float* qkv_w  = (const float*)d_in[3];
  const float* qkv_b  = (const float*)d_in[4];
  const float* proj_w = (const float*)d_in[5];
  const float* proj_b = (const float*)d_in[6];
  const float* rph    = (const float*)d_in[7];
  const float* rpw    = (const float*)d_in[8];
  const float* n2w    = (const float*)d_in[9];
  const float* n2b    = (const float*)d_in[10];
  const float* w1     = (const float*)d_in[11];
  const float* b1     = (const float*)d_in[12];
  const float* w2     = (const float*)d_in[13];
  const float* b2     = (const float*)d_in[14];
  float* out = (float*)d_out;

  char* ws = (char*)d_ws;
  u16* bufT   = (u16*)(ws);             // 38.5 MB: LN1 out -> attn out -> LN2 out
  u16* vTb    = (u16*)(ws + OFF_VT);    // 44.0 MB
  u16* hb     = (u16*)(ws + OFF_H);     // 77.1 MB (aliases vT+; MLP phase only)
  u16* wqkvT  = (u16*)(ws + OFF_W0);
  u16* wprojT = (u16*)(ws + OFF_W1);
  u16* w1T    = (u16*)(ws + OFF_W2);
  u16* w2T    = (u16*)(ws + OFF_W3);
  // q/k live in d_out (dead until PROJ writes x1): 2 x 19,267,584 u16 = 77,070,336 B exact
  u16* qb = (u16*)d_out;
  u16* kb = qb + (size_t)19267584;

  dim3 blk(256), blkg(512);
  transpose_w<<<dim3(72, 24), blk, 0, stream>>>(qkv_w, wqkvT, 768, 2304);
  transpose_w<<<dim3(24, 24), blk, 0, stream>>>(proj_w, wprojT, 768, 768);
  transpose_w<<<dim3(96, 24), blk, 0, stream>>>(w1, w1T, 768, 3072);
  transpose_w<<<dim3(24, 96), blk, 0, stream>>>(w2, w2T, 3072, 768);

  ln_kernel<true><<<6272, blk, 0, stream>>>(x, n1w, n1b, bufT);

  gemm256<EPI_QKV><<<98 * 9, blkg, 0, stream>>>(
      bufT, wqkvT, 768, 0, 98, 9, qkv_b, nullptr, qb, kb, vTb, nullptr);

  attn_fused<<<NWH, blk, 0, stream>>>(qb, kb, vTb, rph, rpw, bufT);

  gemm256<EPI_PROJ><<<98 * 3, blkg, 0, stream>>>(
      bufT, wprojT, 768, 0, 98, 3, proj_b, x, nullptr, nullptr, nullptr, out);

  ln_kernel<false><<<6272, blk, 0, stream>>>(out, n2w, n2b, bufT);

  for (int c = 0; c < 2; c++) {
    const int row0 = c * 12544;
    gemm256<EPI_MLP1><<<49 * 12, blkg, 0, stream>>>(
        bufT + (size_t)row0 * 768, w1T, 768, 0, 49, 12, b1, nullptr, hb, nullptr, nullptr, nullptr);
    gemm256<EPI_MLP2><<<49 * 3, blkg, 0, stream>>>(
        hb, w2T, 3072, row0, 49, 3, b2, out, nullptr, nullptr, nullptr, out);
  }

  (void)in_sizes; (void)n_in; (void)out_size; (void)ws_size;
}

// Round 5
// 955.514 us; speedup vs baseline: 1.0391x; 1.0391x over previous
//
#include <hip/hip_runtime.h>
#include <math.h>

typedef unsigned short u16;
typedef __bf16 bf16x8 __attribute__((ext_vector_type(8)));
typedef float   f32x4 __attribute__((ext_vector_type(4)));
typedef u16     u16x4 __attribute__((ext_vector_type(4)));

// ---------- constants ----------
#define TOK 25088      // B*C*H*W
#define EMB 768
#define NWH 1536       // 128 windows * 12 heads
#define NTOKW 196      // tokens per window
#define PROW 224       // padded vT row length (7 * 32)
#define PPAD 232       // LDS P-strip row pitch (16B-aligned, breaks quad bank collision)
#define GROUP_M 4      // m-blocks per L2-locality supertile

// workspace byte offsets (q/k live in d_out)
#define OFF_VT 38535168ull
#define OFF_W0 127565824ull           // wqkvT 3,538,944
#define OFF_W1 131104768ull           // wprojT 1,179,648
#define OFF_W2 132284416ull           // w1T 4,718,592
#define OFF_W3 137003008ull           // w2T 4,718,592 -> end 141,721,600
#define OFF_H  38535168ull            // hb aliases vT+ (77,070,336 for 12544 rows)

__device__ __forceinline__ u16 f2bf(float f) {
  __bf16 h = (__bf16)f;
  return __builtin_bit_cast(u16, h);
}

__device__ __forceinline__ float bf2f(u16 u) {
  return __builtin_bit_cast(float, (unsigned)u << 16);
}

__device__ __forceinline__ void cp16(void* lds, const void* gsrc) {
  // async global->LDS, 16B per lane; LDS dest is wave-uniform base (+lane*16 implicit)
  __builtin_amdgcn_global_load_lds((const __attribute__((address_space(1))) void*)gsrc,
                                   (__attribute__((address_space(3))) void*)lds,
                                   16, 0, 0);
}

__device__ __forceinline__ f32x4 mfma16(bf16x8 a, bf16x8 b, f32x4 c) {
  return __builtin_amdgcn_mfma_f32_16x16x32_bf16(a, b, c, 0, 0, 0);
}

// Bijective XCD-chunked block map (m204) composed with GROUP_M supertile.
// HW round-robins blockIdx across 8 XCDs; we give each XCD a CONTIGUOUS chunk
// of the supertiled sequence so blocks sharing A/B panels hit the same 4MB L2.
__device__ __forceinline__ void map_block(int b, int nwg, int nbm, int nbn,
                                          int* bm, int* bn) {
  const int q = nwg >> 3, r = nwg & 7;
  const int xcd = b & 7, slot = b >> 3;
  const int logical = (xcd < r ? xcd * (q + 1) : r * (q + 1) + (xcd - r) * q) + slot;
  const int in_group = GROUP_M * nbn;
  const int gid = logical / in_group;
  const int rem0 = logical - gid * in_group;
  const int gm = min(GROUP_M, nbm - gid * GROUP_M);   // tail group
  *bm = gid * GROUP_M + rem0 % gm;
  *bn = rem0 / gm;
}

// ---------- weight transpose fp32[R][C] -> bf16[C][R] ----------
__global__ __launch_bounds__(256)
void transpose_w(const float* __restrict__ src, u16* __restrict__ dst, int R, int C) {
  __shared__ float tile[32][33];
  const int tx = threadIdx.x & 31;
  const int ty = threadIdx.x >> 5;
  const int c0 = blockIdx.x * 32;
  const int r0 = blockIdx.y * 32;
  #pragma unroll
  for (int i = ty; i < 32; i += 8)
    tile[i][tx] = src[(size_t)(r0 + i) * C + c0 + tx];
  __syncthreads();
  #pragma unroll
  for (int i = ty; i < 32; i += 8)
    dst[(size_t)(c0 + i) * R + r0 + tx] = f2bf(tile[tx][i]);
}

// ---------- LayerNorm (wave per row) ----------
template<bool WIN>
__global__ __launch_bounds__(256)
void ln_kernel(const float* __restrict__ x, const float* __restrict__ g,
               const float* __restrict__ b, u16* __restrict__ y) {
  const int wave = threadIdx.x >> 6;
  const int lane = threadIdx.x & 63;
  const int row = blockIdx.x * 4 + wave;
  const float* xr = x + (size_t)row * EMB;
  float4 v[3];
  float s = 0.f, ss = 0.f;
  #pragma unroll
  for (int j = 0; j < 3; j++) {
    v[j] = *(const float4*)&xr[lane * 4 + j * 256];
    s  += v[j].x + v[j].y + v[j].z + v[j].w;
    ss += v[j].x*v[j].x + v[j].y*v[j].y + v[j].z*v[j].z + v[j].w*v[j].w;
  }
  #pragma unroll
  for (int off = 1; off < 64; off <<= 1) {
    s  += __shfl_xor(s, off);
    ss += __shfl_xor(ss, off);
  }
  const float mu = s * (1.0f / 768.0f);
  const float var = ss * (1.0f / 768.0f) - mu * mu;
  const float rs = rsqrtf(var + 1e-5f);
  size_t drow;
  if (WIN) {
    const int bc = row / 3136;
    const int rem = row - bc * 3136;
    const int h = rem / 56;
    const int w = rem - h * 56;
    const int window = bc * 16 + (h / 14) * 4 + (w / 14);
    const int token = (h % 14) * 14 + (w % 14);
    drow = (size_t)window * NTOKW + token;
  } else {
    drow = (size_t)row;
  }
  u16* yr = y + drow * EMB;
  #pragma unroll
  for (int j = 0; j < 3; j++) {
    const int e = lane * 4 + j * 256;
    const float4 gv = *(const float4*)&g[e];
    const float4 bv = *(const float4*)&b[e];
    u16x4 o;
    o[0] = f2bf((v[j].x - mu) * rs * gv.x + bv.x);
    o[1] = f2bf((v[j].y - mu) * rs * gv.y + bv.y);
    o[2] = f2bf((v[j].z - mu) * rs * gv.z + bv.z);
    o[3] = f2bf((v[j].w - mu) * rs * gv.w + bv.w);
    *(u16x4*)&yr[e] = o;
  }
}

#define EPI_QKV  0
#define EPI_PROJ 1
#define EPI_MLP1 2
#define EPI_MLP2 3

// ---------- 256x256 8-phase pipelined bf16 GEMM (T1+T2+T3+T4+T5) ----------
// BK=64, 2 K-tiles/iteration, 8 waves (2M x 4N), per-wave C = 128x64.
// LDS: 2 buffers x (A[256][64] + B[256][64]) bf16 = 128 KiB, 1 block/CU.
// Used for the LARGE grids (QKV 882 blocks, MLP1 588/chunk); relies on
// XCD-chunked mapping for L2-resident staging (latency 200cyc -> 12-deep
// pipeline sustains ~61 B/cyc > 26.4 needed; from HBM it starves at 13.6).
template<int EPI>
__global__ __launch_bounds__(512, 2)
void gemm256(const u16* __restrict__ A, const u16* __restrict__ Bt,
             int K, int moff, int nbm, int nbn,
             const float* __restrict__ bias,
             const float* __restrict__ aux,
             u16* __restrict__ o0, u16* __restrict__ o1, u16* __restrict__ o2,
             float* of) {
  __shared__ __align__(16) u16 lds[2][2][256 * 64];   // [buf][0=A,1=B][row][64]
  const int t = threadIdx.x;
  const int wave = t >> 6;
  const int lane = t & 63;
  const int quad = lane >> 4;
  const int l16 = lane & 15;
  const int wm = wave >> 2;       // 0..1  (M half)
  const int wn = wave & 3;        // 0..3  (N quarter)

  int bm, bn;
  map_block(blockIdx.x, gridDim.x, nbm, nbn, &bm, &bn);
  const int m0 = bm * 256;
  const int n0 = bn * 256;

  // staging: half-tile = 128 rows x 64 cols, chunk c = round*512 + t;
  // row = c>>3, phys chunk = c&7, logical col chunk = (c ^ (c>>3)) & 7
  const int sr0 = t >> 3;
  const int sc0 = ((t ^ (t >> 3)) & 7) * 8;
  const int c1_ = t + 512;
  const int sr1 = c1_ >> 3;
  const int sc1 = ((c1_ ^ (c1_ >> 3)) & 7) * 8;
  const u16* Ag0 = A + (size_t)(m0 + sr0) * K + sc0;
  const u16* Ag1 = A + (size_t)(m0 + sr1) * K + sc1;
  const u16* Bg0 = Bt + (size_t)(n0 + sr0) * K + sc0;
  const u16* Bg1 = Bt + (size_t)(n0 + sr1) * K + sc1;
  const size_t hstep = (size_t)128 * K;    // half-tile row step in source

  // ds_read swizzled chunk offsets (row&7 == l16&7: all row bases are mult of 16)
  const int cK0 = ((quad    ) ^ (l16 & 7)) * 8;   // ksub 0
  const int cK1 = ((4 + quad) ^ (l16 & 7)) * 8;   // ksub 1

  f32x4 acc[8][4];
  const f32x4 zero4 = {0.f, 0.f, 0.f, 0.f};
  #pragma unroll
  for (int i = 0; i < 8; i++)
    #pragma unroll
    for (int j = 0; j < 4; j++) acc[i][j] = zero4;
  bf16x8 bfr[4][2];

#define STG(bb, mat, half, G0, G1, kk) do {                                          \
    cp16(&lds[bb][mat][(half) * 8192 + wave * 512],        (G0) + (half) * hstep + (kk)); \
    cp16(&lds[bb][mat][(half) * 8192 + 4096 + wave * 512], (G1) + (half) * hstep + (kk)); \
  } while (0)

#define LOADB(bb) do {                                                               \
    _Pragma("unroll")                                                                \
    for (int nf = 0; nf < 4; nf++) {                                                 \
      bfr[nf][0] = *(const bf16x8*)&lds[bb][1][(wn * 64 + nf * 16 + l16) * 64 + cK0];\
      bfr[nf][1] = *(const bf16x8*)&lds[bb][1][(wn * 64 + nf * 16 + l16) * 64 + cK1];\
    }                                                                                \
  } while (0)

#define PHASE(bb, slab, PRE, POST) do {                                              \
    const int ar_ = (wm * 128 + (slab) * 32 + l16) * 64;                             \
    bf16x8 a00 = *(const bf16x8*)&lds[bb][0][ar_ + cK0];                             \
    bf16x8 a01 = *(const bf16x8*)&lds[bb][0][ar_ + cK1];                             \
    bf16x8 a10 = *(const bf16x8*)&lds[bb][0][ar_ + 1024 + cK0];                      \
    bf16x8 a11 = *(const bf16x8*)&lds[bb][0][ar_ + 1024 + cK1];                      \
    PRE;                                                                             \
    __builtin_amdgcn_s_barrier();                                                    \
    asm volatile("s_waitcnt lgkmcnt(0)" ::: "memory");                               \
    __builtin_amdgcn_sched_barrier(0);                                               \
    __builtin_amdgcn_s_setprio(1);                                                   \
    _Pragma("unroll")                                                                \
    for (int nf = 0; nf < 4; nf++) {                                                 \
      acc[(slab) * 2    ][nf] = mfma16(a00, bfr[nf][0], acc[(slab) * 2    ][nf]);    \
      acc[(slab) * 2    ][nf] = mfma16(a01, bfr[nf][1], acc[(slab) * 2    ][nf]);    \
      acc[(slab) * 2 + 1][nf] = mfma16(a10, bfr[nf][0], acc[(slab) * 2 + 1][nf]);    \
      acc[(slab) * 2 + 1][nf] = mfma16(a11, bfr[nf][1], acc[(slab) * 2 + 1][nf]);    \
    }                                                                                \
    __builtin_amdgcn_s_setprio(0);                                                   \
    POST;                                                                            \
    __builtin_amdgcn_s_barrier();                                                    \
  } while (0)

  // prologue: B(0)->buf0, A(0)->buf0, B(1)->buf1  (12 loads in flight)
  STG(0, 1, 0, Bg0, Bg1, 0);  STG(0, 1, 1, Bg0, Bg1, 0);
  STG(0, 0, 0, Ag0, Ag1, 0);  STG(0, 0, 1, Ag0, Ag1, 0);
  STG(1, 1, 0, Bg0, Bg1, 64); STG(1, 1, 1, Bg0, Bg1, 64);
  asm volatile("s_waitcnt vmcnt(4)" ::: "memory");   // tile0 landed; B(1) in flight
  __builtin_amdgcn_s_barrier();

  const int T = K >> 7;       // iterations, 2 K-tiles each (K % 128 == 0)
  for (int it = 0; it < T; ++it) {
    const bool nlast = (it < T - 1);
    const int kA1 = (2 * it + 1) << 6;
    const int kT2 = (2 * it + 2) << 6;
    const int kT3 = (2 * it + 3) << 6;

    LOADB(0);
    PHASE(0, 0, STG(1, 0, 0, Ag0, Ag1, kA1), );
    PHASE(0, 1, STG(1, 0, 1, Ag0, Ag1, kA1), );
    PHASE(0, 2, if (nlast) STG(0, 1, 0, Bg0, Bg1, kT2), );
    PHASE(0, 3, if (nlast) STG(0, 1, 1, Bg0, Bg1, kT2),
          if (nlast) { asm volatile("s_waitcnt vmcnt(4)" ::: "memory"); }
          else       { asm volatile("s_waitcnt vmcnt(0)" ::: "memory"); }
          __builtin_amdgcn_sched_barrier(0); );
    LOADB(1);
    PHASE(1, 0, if (nlast) STG(0, 0, 0, Ag0, Ag1, kT2), );
    PHASE(1, 1, if (nlast) STG(0, 0, 1, Ag0, Ag1, kT2), );
    PHASE(1, 2, if (nlast) STG(1, 1, 0, Bg0, Bg1, kT3), );
    PHASE(1, 3, if (nlast) STG(1, 1, 1, Bg0, Bg1, kT3),
          asm volatile("s_waitcnt vmcnt(4)" ::: "memory");
          __builtin_amdgcn_sched_barrier(0); );
  }
#undef STG
#undef LOADB
#undef PHASE

  // epilogue: lane holds D[row = quad*4+r][col = l16] per 16x16 tile
  #pragma unroll
  for (int mf = 0; mf < 8; mf++) {
    const int mb = m0 + wm * 128 + mf * 16 + quad * 4;
    #pragma unroll
    for (int nf = 0; nf < 4; nf++) {
      const int n = n0 + wn * 64 + nf * 16 + l16;
      const float bn_ = bias[n];
      if (EPI == EPI_QKV) {
        const int j3 = n / 768;
        const int rem = n - j3 * 768;
        const int head = rem >> 6;
        const int d = rem & 63;
        if (j3 == 2) {
          // v stored transposed: vT[wh][d][PROW], 4 consecutive tokens per lane
          const int window = mb / 196;
          const int token = mb - window * 196;   // mb%4==0, 196%4==0 -> same window
          const int wh = window * 12 + head;
          u16x4 pv;
          #pragma unroll
          for (int r = 0; r < 4; r++) pv[r] = f2bf(acc[mf][nf][r] + bn_);
          *(u16x4*)&o2[((size_t)wh * 64 + d) * PROW + token] = pv;
        } else {
          u16* dst = (j3 == 0) ? o0 : o1;
          #pragma unroll
          for (int r = 0; r < 4; r++) {
            const int m = mb + r;
            const int window = m / 196;
            const int token = m - window * 196;
            const int wh = window * 12 + head;
            dst[((size_t)wh * NTOKW + token) * 64 + d] = f2bf(acc[mf][nf][r] + bn_);
          }
        }
      } else if (EPI == EPI_MLP1) {
        #pragma unroll
        for (int r = 0; r < 4; r++) {
          const int m = mb + r;
          float v = acc[mf][nf][r] + bn_;
          v = 0.5f * v * (1.0f + erff(v * 0.70710678118654752f));  // exact GELU
          o0[(size_t)m * 3072 + n] = f2bf(v);
        }
      }
    }
  }
}

// ---------- 128x128 bf16 GEMM (m97 structure, 3 blocks/CU) for SMALL grids ----------
// PROJ (1176 blocks) and MLP2 (588/chunk): 256^2 tiles would give 294/147-block
// grids (57% idle CUs); here 3 resident blocks/CU also supply the TLP that
// hides the per-K-step barrier drain.
template<int EPI>
__global__ __launch_bounds__(256, 3)
void gemm_bt(const u16* __restrict__ A, const u16* __restrict__ Bt,
             int K, int moff, int nbm, int nbn,
             const float* __restrict__ bias,
             const float* __restrict__ aux,
             u16* __restrict__ o0,
             float* of) {
  __shared__ __align__(16) u16 lsA[4096];  // 128 x 32
  __shared__ __align__(16) u16 lsB[4096];
  const int t = threadIdx.x;
  const int wave = t >> 6;
  const int lane = t & 63;
  const int quad = lane >> 4;
  const int l16 = lane & 15;

  int bm, bn;
  map_block(blockIdx.x, gridDim.x, nbm, nbn, &bm, &bn);
  const int m0 = bm * 128;
  const int n0 = bn * 128;

  const int wm = (wave >> 1) * 64;
  const int wn = (wave & 1) * 64;

  // staging source with XOR bank swizzle: row = t>>2, logical chunk = (t&3) ^ ((row>>1)&3)
  const int srow = t >> 2;
  const int scol = (((t & 3) ^ ((t >> 3) & 3))) * 8;
  const u16* Ag = A + (size_t)(m0 + srow) * K + scol;
  const u16* Bg = Bt + (size_t)(n0 + srow) * K + scol;
  u16* lA0 = lsA + wave * 512;
  u16* lA1 = lsA + 2048 + wave * 512;
  u16* lB0 = lsB + wave * 512;
  u16* lB1 = lsB + 2048 + wave * 512;

  // read-side swizzled chunk offset (row parity pattern = l16 parity; wm/wn mult of 16)
  const int kc = (quad ^ ((l16 >> 1) & 3)) * 8;

  f32x4 acc[4][4];
  const f32x4 zero4 = {0.f, 0.f, 0.f, 0.f};
  #pragma unroll
  for (int i = 0; i < 4; i++)
    #pragma unroll
    for (int j = 0; j < 4; j++) acc[i][j] = zero4;

  for (int k0 = 0; k0 < K; k0 += 32) {
    cp16(lA0, Ag + k0);
    cp16(lA1, Ag + (size_t)64 * K + k0);
    cp16(lB0, Bg + k0);
    cp16(lB1, Bg + (size_t)64 * K + k0);
    __syncthreads();           // drains vmcnt for global_load_lds
    bf16x8 af[4], bfr[4];
    #pragma unroll
    for (int i = 0; i < 4; i++)
      af[i] = *(const bf16x8*)&lsA[(wm + i * 16 + l16) * 32 + kc];
    #pragma unroll
    for (int j = 0; j < 4; j++)
      bfr[j] = *(const bf16x8*)&lsB[(wn + j * 16 + l16) * 32 + kc];
    #pragma unroll
    for (int i = 0; i < 4; i++)
      #pragma unroll
      for (int j = 0; j < 4; j++)
        acc[i][j] = mfma16(af[i], bfr[j], acc[i][j]);
    __syncthreads();
  }

  // epilogue: lane holds D[row = quad*4+r][col = l16] per 16x16 tile
  #pragma unroll
  for (int i = 0; i < 4; i++) {
    const int mb = m0 + wm + i * 16 + quad * 4;
    #pragma unroll
    for (int j = 0; j < 4; j++) {
      const int n = n0 + wn + j * 16 + l16;
      const float bn_ = bias[n];
      if (EPI == EPI_PROJ) {
        #pragma unroll
        for (int r = 0; r < 4; r++) {
          const int m = mb + r;
          const int window = m / 196;
          const int token = m - window * 196;
          const int bc = window >> 4;
          const int wi = window & 15;
          const int th = token / 14;
          const int tw = token - th * 14;
          const int h = (wi >> 2) * 14 + th;
          const int w = (wi & 3) * 14 + tw;
          const size_t flat = (((size_t)bc * 56 + h) * 56 + w) * 768 + n;
          of[flat] = acc[i][j][r] + bn_ + aux[flat];   // x1 = proj + bias + shortcut
        }
      } else {  // EPI_MLP2
        #pragma unroll
        for (int r = 0; r < 4; r++) {
          const int m = mb + r + moff;
          const size_t idx = (size_t)m * 768 + n;
          of[idx] = acc[i][j][r] + bn_ + aux[idx];     // out = z + x1
        }
      }
    }
  }
}

// ---------- fused attention: S=scale*qk^T+rel, softmax, O=P@V — one kernel ----------
// lsK XOR-swizzled: physical chunk c of row holds logical c^(row&7) (8 chunks/row).
__global__ __launch_bounds__(256, 2)
void attn_fused(const u16* __restrict__ q, const u16* __restrict__ k,
                const u16* __restrict__ vT,
                const float* __restrict__ rph, const float* __restrict__ rpw,
                u16* __restrict__ out) {
  __shared__ __align__(16) u16 lsK[208 * 64];   // 26624 B (rows 196.. stale; cols masked)
  __shared__ __align__(16) u16 relh[16 * 224];  // bf16 [kh][i]  7168 B
  __shared__ __align__(16) u16 relw[16 * 224];  // bf16 [kw][i]  7168 B
  __shared__ __align__(16) u16 lsP[4][16 * PPAD]; // 29696 B, wave-private strips
  const int t = threadIdx.x;
  const int wave = t >> 6;
  const int lane = t & 63;
  const int quad = lane >> 4;
  const int l16 = lane & 15;
  const int wh = blockIdx.x;
  const u16* qg = q + (size_t)wh * (NTOKW * 64);
  const u16* kg = k + (size_t)wh * (NTOKW * 64);
  const u16* vg = vT + (size_t)wh * 64 * PROW;
  const int window = wh / 12;
  const int head = wh - window * 12;

  // stage k rows 0..195 with XOR source swizzle (chunk c of row r <- logical c^(r&7))
  #pragma unroll
  for (int i = 0; i < 6; i++) {
    const int chunk = i * 256 + t;
    const int goff = ((chunk & ~7) | ((chunk ^ (chunk >> 3)) & 7)) * 8;
    cp16(lsK + (i * 256 + wave * 64) * 8, kg + goff);
  }
  if (t < 32) {
    const int chunk = 1536 + t;
    const int goff = ((chunk & ~7) | ((chunk ^ (chunk >> 3)) & 7)) * 8;
    cp16(lsK + 1536 * 8, kg + goff);
  }

  // rel_h / rel_w tables via MFMA (bf16 in LDS)
  const f32x4 zero4 = {0.f, 0.f, 0.f, 0.f};
  for (int tile = wave; tile < 14; tile += 4) {
    f32x4 ah = zero4, aw = zero4;
    const int ridx = min(max(tile - l16 + 13, 0), 26);  // clamp (l16>=14 cols discarded)
    #pragma unroll
    for (int ks = 0; ks < 2; ks++) {
      const int ko = ks * 32 + quad * 8;
      bf16x8 aq_h = *(const bf16x8*)&qg[(tile * 14 + l16) * 64 + ko];
      bf16x8 aq_w = *(const bf16x8*)&qg[(tile + 14 * l16) * 64 + ko];
      bf16x8 bh, bw;
      const float* ph = rph + ridx * 64 + ko;
      const float* pw = rpw + ridx * 64 + ko;
      #pragma unroll
      for (int e = 0; e < 8; e++) { bh[e] = (__bf16)ph[e]; bw[e] = (__bf16)pw[e]; }
      ah = mfma16(aq_h, bh, ah);
      aw = mfma16(aq_w, bw, aw);
    }
    #pragma unroll
    for (int r = 0; r < 4; r++) {
      const int m = quad * 4 + r;
      if (m < 14) {
        relh[l16 * 224 + tile * 14 + m] = f2bf(ah[r]);
        relw[l16 * 224 + tile + 14 * m] = f2bf(aw[r]);
      }
    }
  }
  __syncthreads();   // drains cp16 vmcnt + publishes rel tables

  const float scale = 0.125f;  // 64^-0.5
  const int sw = l16 & 7;      // lsK read swizzle (row&7 == l16&7 for rows = jt*16+l16)
  u16* myP = &lsP[wave][0];
  for (int s = wave; s < 13; s += 4) {
    bf16x8 aq[2];
    #pragma unroll
    for (int ks = 0; ks < 2; ks++)
      aq[ks] = *(const bf16x8*)&qg[(s * 16 + l16) * 64 + ks * 32 + quad * 8];
    f32x4 acc[13];
    #pragma unroll
    for (int jt = 0; jt < 13; jt++) {
      f32x4 a = zero4;
      a = mfma16(aq[0], *(const bf16x8*)&lsK[(jt * 16 + l16) * 64 + (quad ^ sw) * 8], a);
      a = mfma16(aq[1], *(const bf16x8*)&lsK[(jt * 16 + l16) * 64 + ((quad + 4) ^ sw) * 8], a);
      acc[jt] = a;
    }
    f32x4 mx = {-1e30f, -1e30f, -1e30f, -1e30f};
    #pragma unroll
    for (int jt = 0; jt < 13; jt++) {
      const int col = jt * 16 + l16;
      if (col < 196) {
        const int kh = col / 14;
        const int kw = col - kh * 14;
        const u16x4 rhu = *(const u16x4*)&relh[kh * 224 + s * 16 + quad * 4];
        const u16x4 rwu = *(const u16x4*)&relw[kw * 224 + s * 16 + quad * 4];
        #pragma unroll
        for (int r = 0; r < 4; r++)
          acc[jt][r] = acc[jt][r] * scale + bf2f(rhu[r]) + bf2f(rwu[r]);
      } else {
        acc[jt] = (f32x4){-1e30f, -1e30f, -1e30f, -1e30f};  // full overwrite: kills stale LDS
      }
      #pragma unroll
      for (int r = 0; r < 4; r++) mx[r] = fmaxf(mx[r], acc[jt][r]);
    }
    // rows live per-quad (xor masks <16 stay inside the 16-lane group)
    #pragma unroll
    for (int off = 1; off < 16; off <<= 1)
      #pragma unroll
      for (int r = 0; r < 4; r++) mx[r] = fmaxf(mx[r], __shfl_xor(mx[r], off));
    f32x4 sum = zero4;
    #pragma unroll
    for (int jt = 0; jt < 13; jt++)
      #pragma unroll
      for (int r = 0; r < 4; r++) {
        const float p = exp2f((acc[jt][r] - mx[r]) * 1.4426950408889634f);
        acc[jt][r] = p;
        sum[r] += p;
      }
    #pragma unroll
    for (int off = 1; off < 16; off <<= 1)
      #pragma unroll
      for (int r = 0; r < 4; r++) sum[r] += __shfl_xor(sum[r], off);
    // write P strip (wave-private; rows = quad*4+r, cols = jt*16+l16)
    #pragma unroll
    for (int r = 0; r < 4; r++) {
      const float rinv = 1.0f / sum[r];
      const int prow = (quad * 4 + r) * PPAD;
      #pragma unroll
      for (int jt = 0; jt < 13; jt++)
        myP[prow + jt * 16 + l16] = f2bf(acc[jt][r] * rinv);
      myP[prow + 208 + l16] = 0;   // zero pad cols 208..223
    }
    asm volatile("s_waitcnt lgkmcnt(0)" ::: "memory");  // P strip visible to own wave
    // O = P @ V ; A-frag from LDS strip, B-frag (vT) from global (L1/L2-resident)
    f32x4 acco[4] = {zero4, zero4, zero4, zero4};
    #pragma unroll
    for (int ks = 0; ks < 7; ks++) {
      bf16x8 ap = *(const bf16x8*)&myP[l16 * PPAD + ks * 32 + quad * 8];
      #pragma unroll
      for (int nt = 0; nt < 4; nt++) {
        bf16x8 bv = *(const bf16x8*)&vg[(nt * 16 + l16) * PROW + ks * 32 + quad * 8];
        acco[nt] = mfma16(ap, bv, acco[nt]);
      }
    }
    #pragma unroll
    for (int nt = 0; nt < 4; nt++)
      #pragma unroll
      for (int r = 0; r < 4; r++) {
        const int i = s * 16 + quad * 4 + r;
        if (i < 196)
          out[((size_t)window * NTOKW + i) * EMB + head * 64 + nt * 16 + l16] =
              f2bf(acco[nt][r]);
      }
  }
}

// ---------- launch ----------
extern "C" void kernel_launch(void* const* d_in, const int* in_sizes, int n_in,
                              void* d_out, int out_size, void* d_ws, size_t ws_size,
                              hipStream_t stream) {
  const float* x      = (const float*)d_in[0];
  const float* n1w    = (const float*)d_in[1];
  const float* n1b    = (const float*)d_in[2];
  const float* qkv_w  = (const float*)d_in[3];
  const float* qkv_b  = (const float*)d_in[4];
  const float* proj_w = (const float*)d_in[5];
  const float* proj_b = (const float*)d_in[6];
  const float* rph    = (const float*)d_in[7];
  const float* rpw    = (const float*)d_in[8];
  const float* n2w    = (const float*)d_in[9];
  const float* n2b    = (const float*)d_in[10];
  const float* w1     = (const float*)d_in[11];
  const float* b1     = (const float*)d_in[12];
  const float* w2     = (const float*)d_in[13];
  const float* b2     = (const float*)d_in[14];
  float* out = (float*)d_out;

  char* ws = (char*)d_ws;
  u16* bufT   = (u16*)(ws);             // 38.5 MB: LN1 out -> attn out -> LN2 out
  u16* vTb    = (u16*)(ws + OFF_VT);    // 44.0 MB
  u16* hb     = (u16*)(ws + OFF_H);     // 77.1 MB (aliases vT+; MLP phase only)
  u16* wqkvT  = (u16*)(ws + OFF_W0);
  u16* wprojT = (u16*)(ws + OFF_W1);
  u16* w1T    = (u16*)(ws + OFF_W2);
  u16* w2T    = (u16*)(ws + OFF_W3);
  // q/k live in d_out (dead until PROJ writes x1): 2 x 19,267,584 u16 = 77,070,336 B exact
  u16* qb = (u16*)d_out;
  u16* kb = qb + (size_t)19267584;

  dim3 blk(256), blkg(512);
  transpose_w<<<dim3(72, 24), blk, 0, stream>>>(qkv_w, wqkvT, 768, 2304);
  transpose_w<<<dim3(24, 24), blk, 0, stream>>>(proj_w, wprojT, 768, 768);
  transpose_w<<<dim3(96, 24), blk, 0, stream>>>(w1, w1T, 768, 3072);
  transpose_w<<<dim3(24, 96), blk, 0, stream>>>(w2, w2T, 3072, 768);

  ln_kernel<true><<<6272, blk, 0, stream>>>(x, n1w, n1b, bufT);

  gemm256<EPI_QKV><<<98 * 9, blkg, 0, stream>>>(
      bufT, wqkvT, 768, 0, 98, 9, qkv_b, nullptr, qb, kb, vTb, nullptr);

  attn_fused<<<NWH, blk, 0, stream>>>(qb, kb, vTb, rph, rpw, bufT);

  gemm_bt<EPI_PROJ><<<196 * 6, blk, 0, stream>>>(
      bufT, wprojT, 768, 0, 196, 6, proj_b, x, nullptr, out);

  ln_kernel<false><<<6272, blk, 0, stream>>>(out, n2w, n2b, bufT);

  for (int c = 0; c < 2; c++) {
    const int row0 = c * 12544;
    gemm256<EPI_MLP1><<<49 * 12, blkg, 0, stream>>>(
        bufT + (size_t)row0 * 768, w1T, 768, 0, 49, 12, b1, nullptr, hb, nullptr, nullptr, nullptr);
    gemm_bt<EPI_MLP2><<<98 * 6, blk, 0, stream>>>(
        hb, w2T, 3072, row0, 98, 6, b2, out, nullptr, out);
  }

  (void)in_sizes; (void)n_in; (void)out_size; (void)ws_size;
}

// Round 7
// 844.717 us; speedup vs baseline: 1.1754x; 1.1312x over previous
//
#include <hip/hip_runtime.h>
#include <math.h>

typedef unsigned short u16;
typedef __bf16 bf16x8 __attribute__((ext_vector_type(8)));
typedef float   f32x4 __attribute__((ext_vector_type(4)));
typedef u16     u16x4 __attribute__((ext_vector_type(4)));

// ---------- constants ----------
#define TOK 25088      // B*C*H*W
#define EMB 768
#define NWH 1536       // 128 windows * 12 heads
#define NTOKW 196      // tokens per window
#define PROW 224       // padded vT row length (7 * 32)
#define PPAD 232       // LDS P-strip row pitch (16B-aligned, breaks quad bank collision)
#define GROUP_M 4      // m-blocks per L2-locality supertile

// workspace byte offsets (q/k live in d_out)
#define OFF_VT 38535168ull
#define OFF_W0 127565824ull           // wqkvT 3,538,944
#define OFF_W1 131104768ull           // wprojT 1,179,648
#define OFF_W2 132284416ull           // w1T 4,718,592
#define OFF_W3 137003008ull           // w2T 4,718,592 -> end 141,721,600
#define OFF_H  38535168ull            // hb aliases vT+ (77,070,336 for 12544 rows)

__device__ __forceinline__ u16 f2bf(float f) {
  __bf16 h = (__bf16)f;
  return __builtin_bit_cast(u16, h);
}

__device__ __forceinline__ float bf2f(u16 u) {
  return __builtin_bit_cast(float, (unsigned)u << 16);
}

__device__ __forceinline__ void cp16(void* lds, const void* gsrc) {
  // async global->LDS, 16B per lane; LDS dest is wave-uniform base (+lane*16 implicit)
  __builtin_amdgcn_global_load_lds((const __attribute__((address_space(1))) void*)gsrc,
                                   (__attribute__((address_space(3))) void*)lds,
                                   16, 0, 0);
}

__device__ __forceinline__ f32x4 mfma16(bf16x8 a, bf16x8 b, f32x4 c) {
  return __builtin_amdgcn_mfma_f32_16x16x32_bf16(a, b, c, 0, 0, 0);
}

// Bijective XCD-chunked block map (m204) composed with GROUP_M supertile.
// Measured (R5): FETCH 97.9->84.6 MB on QKV — keep (no time cost).
__device__ __forceinline__ void map_block(int b, int nwg, int nbm, int nbn,
                                          int* bm, int* bn) {
  const int q = nwg >> 3, r = nwg & 7;
  const int xcd = b & 7, slot = b >> 3;
  const int logical = (xcd < r ? xcd * (q + 1) : r * (q + 1) + (xcd - r) * q) + slot;
  const int in_group = GROUP_M * nbn;
  const int gid = logical / in_group;
  const int rem0 = logical - gid * in_group;
  const int gm = min(GROUP_M, nbm - gid * GROUP_M);   // tail group
  *bm = gid * GROUP_M + rem0 % gm;
  *bn = rem0 / gm;
}

// ---------- weight transpose fp32[R][C] -> bf16[C][R] ----------
__global__ __launch_bounds__(256)
void transpose_w(const float* __restrict__ src, u16* __restrict__ dst, int R, int C) {
  __shared__ float tile[32][33];
  const int tx = threadIdx.x & 31;
  const int ty = threadIdx.x >> 5;
  const int c0 = blockIdx.x * 32;
  const int r0 = blockIdx.y * 32;
  #pragma unroll
  for (int i = ty; i < 32; i += 8)
    tile[i][tx] = src[(size_t)(r0 + i) * C + c0 + tx];
  __syncthreads();
  #pragma unroll
  for (int i = ty; i < 32; i += 8)
    dst[(size_t)(c0 + i) * R + r0 + tx] = f2bf(tile[tx][i]);
}

// ---------- LayerNorm (wave per row) ----------
template<bool WIN>
__global__ __launch_bounds__(256)
void ln_kernel(const float* __restrict__ x, const float* __restrict__ g,
               const float* __restrict__ b, u16* __restrict__ y) {
  const int wave = threadIdx.x >> 6;
  const int lane = threadIdx.x & 63;
  const int row = blockIdx.x * 4 + wave;
  const float* xr = x + (size_t)row * EMB;
  float4 v[3];
  float s = 0.f, ss = 0.f;
  #pragma unroll
  for (int j = 0; j < 3; j++) {
    v[j] = *(const float4*)&xr[lane * 4 + j * 256];
    s  += v[j].x + v[j].y + v[j].z + v[j].w;
    ss += v[j].x*v[j].x + v[j].y*v[j].y + v[j].z*v[j].z + v[j].w*v[j].w;
  }
  #pragma unroll
  for (int off = 1; off < 64; off <<= 1) {
    s  += __shfl_xor(s, off);
    ss += __shfl_xor(ss, off);
  }
  const float mu = s * (1.0f / 768.0f);
  const float var = ss * (1.0f / 768.0f) - mu * mu;
  const float rs = rsqrtf(var + 1e-5f);
  size_t drow;
  if (WIN) {
    const int bc = row / 3136;
    const int rem = row - bc * 3136;
    const int h = rem / 56;
    const int w = rem - h * 56;
    const int window = bc * 16 + (h / 14) * 4 + (w / 14);
    const int token = (h % 14) * 14 + (w % 14);
    drow = (size_t)window * NTOKW + token;
  } else {
    drow = (size_t)row;
  }
  u16* yr = y + drow * EMB;
  #pragma unroll
  for (int j = 0; j < 3; j++) {
    const int e = lane * 4 + j * 256;
    const float4 gv = *(const float4*)&g[e];
    const float4 bv = *(const float4*)&b[e];
    u16x4 o;
    o[0] = f2bf((v[j].x - mu) * rs * gv.x + bv.x);
    o[1] = f2bf((v[j].y - mu) * rs * gv.y + bv.y);
    o[2] = f2bf((v[j].z - mu) * rs * gv.z + bv.z);
    o[3] = f2bf((v[j].w - mu) * rs * gv.w + bv.w);
    *(u16x4*)&yr[e] = o;
  }
}

#define EPI_QKV  0
#define EPI_PROJ 1
#define EPI_MLP1 2
#define EPI_MLP2 3

// ---------- 128x128 bf16 GEMM, BK=64, XOR-swizzled LDS, fused epilogues ----------
// m97 structure (proven best at short K: 920.8us baseline vs 992.9 with 256^2
// 8-phase) upgraded BK 32->64: 32 MFMA per barrier-pair instead of 16, halving
// the per-iteration barrier-drain share. LDS 32KB -> still >=3 blocks/CU of TLP.
// Swizzle: LDS phys chunk p of row r holds logical chunk p^(r&7) (8x16B/row);
// applied on the per-lane GLOBAL source of cp16 (dest linear, rule #21) and on
// the ds_read address. Same pattern as R1's gemm256 (measured 0 bank conflicts).
template<int EPI>
__global__ __launch_bounds__(256, 3)
void gemm_bt64(const u16* __restrict__ A, const u16* __restrict__ Bt,
               int K, int moff, int nbm, int nbn,
               const float* __restrict__ bias,
               const float* __restrict__ aux,   // PROJ: x (shortcut); MLP2: x1 (=d_out)
               u16* __restrict__ o0, u16* __restrict__ o1, u16* __restrict__ o2,
               float* of) {
  __shared__ __align__(16) u16 lsA[8192];  // 128 x 64
  __shared__ __align__(16) u16 lsB[8192];
  const int t = threadIdx.x;
  const int wave = t >> 6;
  const int lane = t & 63;
  const int quad = lane >> 4;
  const int l16 = lane & 15;

  int bm, bn;
  map_block(blockIdx.x, gridDim.x, nbm, nbn, &bm, &bn);
  const int m0 = bm * 128;
  const int n0 = bn * 128;

  const int wm = (wave >> 1) * 64;
  const int wn = (wave & 1) * 64;

  // staging: chunk c = issue*256 + t; row = c>>3 = 32*issue + (t>>3); phys = t&7;
  // logical col chunk = (t ^ (t>>3)) & 7  (issue-independent since 32*issue%8==0)
  const int sr = t >> 3;
  const int sc = ((t ^ (t >> 3)) & 7) * 8;
  const u16* Ag = A + (size_t)(m0 + sr) * K + sc;
  const u16* Bg = Bt + (size_t)(n0 + sr) * K + sc;
  u16* dA = lsA + wave * 512;   // wave base within each 4KB issue block
  u16* dB = lsB + wave * 512;

  // ds_read swizzled chunk offsets (row&7 == l16&7: row bases are multiples of 16)
  const int cK0 = ((quad    ) ^ (l16 & 7)) * 8;
  const int cK1 = ((4 + quad) ^ (l16 & 7)) * 8;

  f32x4 acc[4][4];
  const f32x4 zero4 = {0.f, 0.f, 0.f, 0.f};
  #pragma unroll
  for (int i = 0; i < 4; i++)
    #pragma unroll
    for (int j = 0; j < 4; j++) acc[i][j] = zero4;

  for (int k0 = 0; k0 < K; k0 += 64) {
    #pragma unroll
    for (int i = 0; i < 4; i++) {
      cp16(dA + i * 2048, Ag + (size_t)(32 * i) * K + k0);
      cp16(dB + i * 2048, Bg + (size_t)(32 * i) * K + k0);
    }
    __syncthreads();           // drains vmcnt for global_load_lds
    #pragma unroll
    for (int ks = 0; ks < 2; ks++) {
      const int kc = ks ? cK1 : cK0;
      bf16x8 af[4], bfr[4];
      #pragma unroll
      for (int i = 0; i < 4; i++)
        af[i] = *(const bf16x8*)&lsA[(wm + i * 16 + l16) * 64 + kc];
      #pragma unroll
      for (int j = 0; j < 4; j++)
        bfr[j] = *(const bf16x8*)&lsB[(wn + j * 16 + l16) * 64 + kc];
      #pragma unroll
      for (int i = 0; i < 4; i++)
        #pragma unroll
        for (int j = 0; j < 4; j++)
          acc[i][j] = mfma16(af[i], bfr[j], acc[i][j]);
    }
    __syncthreads();
  }

  // epilogue: lane holds D[row = quad*4+r][col = l16] per 16x16 tile
  #pragma unroll
  for (int i = 0; i < 4; i++) {
    const int mb = m0 + wm + i * 16 + quad * 4;
    #pragma unroll
    for (int j = 0; j < 4; j++) {
      const int n = n0 + wn + j * 16 + l16;
      const float bn_ = bias[n];
      if (EPI == EPI_QKV) {
        const int j3 = n / 768;
        const int rem = n - j3 * 768;
        const int head = rem >> 6;
        const int d = rem & 63;
        if (j3 == 2) {
          // v stored transposed: vT[wh][d][PROW], 4 consecutive tokens per lane
          const int window = mb / 196;
          const int token = mb - window * 196;   // mb%4==0, 196%4==0 -> same window
          const int wh = window * 12 + head;
          u16x4 pv;
          #pragma unroll
          for (int r = 0; r < 4; r++) pv[r] = f2bf(acc[i][j][r] + bn_);
          *(u16x4*)&o2[((size_t)wh * 64 + d) * PROW + token] = pv;
        } else {
          u16* dst = (j3 == 0) ? o0 : o1;
          #pragma unroll
          for (int r = 0; r < 4; r++) {
            const int m = mb + r;
            const int window = m / 196;
            const int token = m - window * 196;
            const int wh = window * 12 + head;
            dst[((size_t)wh * NTOKW + token) * 64 + d] = f2bf(acc[i][j][r] + bn_);
          }
        }
      } else if (EPI == EPI_PROJ) {
        #pragma unroll
        for (int r = 0; r < 4; r++) {
          const int m = mb + r;
          const int window = m / 196;
          const int token = m - window * 196;
          const int bc = window >> 4;
          const int wi = window & 15;
          const int th = token / 14;
          const int tw = token - th * 14;
          const int h = (wi >> 2) * 14 + th;
          const int w = (wi & 3) * 14 + tw;
          const size_t flat = (((size_t)bc * 56 + h) * 56 + w) * 768 + n;
          of[flat] = acc[i][j][r] + bn_ + aux[flat];   // x1 = proj + bias + shortcut
        }
      } else if (EPI == EPI_MLP1) {
        #pragma unroll
        for (int r = 0; r < 4; r++) {
          const int m = mb + r;
          float v = acc[i][j][r] + bn_;
          v = 0.5f * v * (1.0f + erff(v * 0.70710678118654752f));  // exact GELU
          o0[(size_t)m * 3072 + n] = f2bf(v);
        }
      } else {  // EPI_MLP2
        #pragma unroll
        for (int r = 0; r < 4; r++) {
          const int m = mb + r + moff;
          const size_t idx = (size_t)m * 768 + n;
          of[idx] = acc[i][j][r] + bn_ + aux[idx];     // out = z + x1
        }
      }
    }
  }
}

// ---------- fused attention: S=scale*qk^T+rel, softmax, O=P@V — one kernel ----------
// lsK XOR-swizzled: physical chunk c of row holds logical c^(row&7) (8 chunks/row).
__global__ __launch_bounds__(256, 2)
void attn_fused(const u16* __restrict__ q, const u16* __restrict__ k,
                const u16* __restrict__ vT,
                const float* __restrict__ rph, const float* __restrict__ rpw,
                u16* __restrict__ out) {
  __shared__ __align__(16) u16 lsK[208 * 64];   // 26624 B (rows 196.. stale; cols masked)
  __shared__ __align__(16) u16 relh[16 * 224];  // bf16 [kh][i]  7168 B
  __shared__ __align__(16) u16 relw[16 * 224];  // bf16 [kw][i]  7168 B
  __shared__ __align__(16) u16 lsP[4][16 * PPAD]; // 29696 B, wave-private strips
  const int t = threadIdx.x;
  const int wave = t >> 6;
  const int lane = t & 63;
  const int quad = lane >> 4;
  const int l16 = lane & 15;
  const int wh = blockIdx.x;
  const u16* qg = q + (size_t)wh * (NTOKW * 64);
  const u16* kg = k + (size_t)wh * (NTOKW * 64);
  const u16* vg = vT + (size_t)wh * 64 * PROW;
  const int window = wh / 12;
  const int head = wh - window * 12;

  // stage k rows 0..195 with XOR source swizzle (chunk c of row r <- logical c^(r&7))
  #pragma unroll
  for (int i = 0; i < 6; i++) {
    const int chunk = i * 256 + t;
    const int goff = ((chunk & ~7) | ((chunk ^ (chunk >> 3)) & 7)) * 8;
    cp16(lsK + (i * 256 + wave * 64) * 8, kg + goff);
  }
  if (t < 32) {
    const int chunk = 1536 + t;
    const int goff = ((chunk & ~7) | ((chunk ^ (chunk >> 3)) & 7)) * 8;
    cp16(lsK + 1536 * 8, kg + goff);
  }

  // rel_h / rel_w tables via MFMA (bf16 in LDS)
  const f32x4 zero4 = {0.f, 0.f, 0.f, 0.f};
  for (int tile = wave; tile < 14; tile += 4) {
    f32x4 ah = zero4, aw = zero4;
    const int ridx = min(max(tile - l16 + 13, 0), 26);  // clamp (l16>=14 cols discarded)
    #pragma unroll
    for (int ks = 0; ks < 2; ks++) {
      const int ko = ks * 32 + quad * 8;
      bf16x8 aq_h = *(const bf16x8*)&qg[(tile * 14 + l16) * 64 + ko];
      bf16x8 aq_w = *(const bf16x8*)&qg[(tile + 14 * l16) * 64 + ko];
      bf16x8 bh, bw;
      const float* ph = rph + ridx * 64 + ko;
      const float* pw = rpw + ridx * 64 + ko;
      #pragma unroll
      for (int e = 0; e < 8; e++) { bh[e] = (__bf16)ph[e]; bw[e] = (__bf16)pw[e]; }
      ah = mfma16(aq_h, bh, ah);
      aw = mfma16(aq_w, bw, aw);
    }
    #pragma unroll
    for (int r = 0; r < 4; r++) {
      const int m = quad * 4 + r;
      if (m < 14) {
        relh[l16 * 224 + tile * 14 + m] = f2bf(ah[r]);
        relw[l16 * 224 + tile + 14 * m] = f2bf(aw[r]);
      }
    }
  }
  __syncthreads();   // drains cp16 vmcnt + publishes rel tables

  const float scale = 0.125f;  // 64^-0.5
  const int sw = l16 & 7;      // lsK read swizzle (row&7 == l16&7 for rows = jt*16+l16)
  u16* myP = &lsP[wave][0];
  for (int s = wave; s < 13; s += 4) {
    bf16x8 aq[2];
    #pragma unroll
    for (int ks = 0; ks < 2; ks++)
      aq[ks] = *(const bf16x8*)&qg[(s * 16 + l16) * 64 + ks * 32 + quad * 8];
    f32x4 acc[13];
    #pragma unroll
    for (int jt = 0; jt < 13; jt++) {
      f32x4 a = zero4;
      a = mfma16(aq[0], *(const bf16x8*)&lsK[(jt * 16 + l16) * 64 + (quad ^ sw) * 8], a);
      a = mfma16(aq[1], *(const bf16x8*)&lsK[(jt * 16 + l16) * 64 + ((quad + 4) ^ sw) * 8], a);
      acc[jt] = a;
    }
    f32x4 mx = {-1e30f, -1e30f, -1e30f, -1e30f};
    #pragma unroll
    for (int jt = 0; jt < 13; jt++) {
      const int col = jt * 16 + l16;
      if (col < 196) {
        const int kh = col / 14;
        const int kw = col - kh * 14;
        const u16x4 rhu = *(const u16x4*)&relh[kh * 224 + s * 16 + quad * 4];
        const u16x4 rwu = *(const u16x4*)&relw[kw * 224 + s * 16 + quad * 4];
        #pragma unroll
        for (int r = 0; r < 4; r++)
          acc[jt][r] = acc[jt][r] * scale + bf2f(rhu[r]) + bf2f(rwu[r]);
      } else {
        acc[jt] = (f32x4){-1e30f, -1e30f, -1e30f, -1e30f};  // full overwrite: kills stale LDS
      }
      #pragma unroll
      for (int r = 0; r < 4; r++) mx[r] = fmaxf(mx[r], acc[jt][r]);
    }
    // rows live per-quad (xor masks <16 stay inside the 16-lane group)
    #pragma unroll
    for (int off = 1; off < 16; off <<= 1)
      #pragma unroll
      for (int r = 0; r < 4; r++) mx[r] = fmaxf(mx[r], __shfl_xor(mx[r], off));
    f32x4 sum = zero4;
    #pragma unroll
    for (int jt = 0; jt < 13; jt++)
      #pragma unroll
      for (int r = 0; r < 4; r++) {
        const float p = exp2f((acc[jt][r] - mx[r]) * 1.4426950408889634f);
        acc[jt][r] = p;
        sum[r] += p;
      }
    #pragma unroll
    for (int off = 1; off < 16; off <<= 1)
      #pragma unroll
      for (int r = 0; r < 4; r++) sum[r] += __shfl_xor(sum[r], off);
    // write P strip (wave-private; rows = quad*4+r, cols = jt*16+l16)
    #pragma unroll
    for (int r = 0; r < 4; r++) {
      const float rinv = 1.0f / sum[r];
      const int prow = (quad * 4 + r) * PPAD;
      #pragma unroll
      for (int jt = 0; jt < 13; jt++)
        myP[prow + jt * 16 + l16] = f2bf(acc[jt][r] * rinv);
      myP[prow + 208 + l16] = 0;   // zero pad cols 208..223
    }
    asm volatile("s_waitcnt lgkmcnt(0)" ::: "memory");  // P strip visible to own wave
    // O = P @ V ; A-frag from LDS strip, B-frag (vT) from global (L1/L2-resident)
    f32x4 acco[4] = {zero4, zero4, zero4, zero4};
    #pragma unroll
    for (int ks = 0; ks < 7; ks++) {
      bf16x8 ap = *(const bf16x8*)&myP[l16 * PPAD + ks * 32 + quad * 8];
      #pragma unroll
      for (int nt = 0; nt < 4; nt++) {
        bf16x8 bv = *(const bf16x8*)&vg[(nt * 16 + l16) * PROW + ks * 32 + quad * 8];
        acco[nt] = mfma16(ap, bv, acco[nt]);
      }
    }
    #pragma unroll
    for (int nt = 0; nt < 4; nt++)
      #pragma unroll
      for (int r = 0; r < 4; r++) {
        const int i = s * 16 + quad * 4 + r;
        if (i < 196)
          out[((size_t)window * NTOKW + i) * EMB + head * 64 + nt * 16 + l16] =
              f2bf(acco[nt][r]);
      }
  }
}

// ---------- launch ----------
extern "C" void kernel_launch(void* const* d_in, const int* in_sizes, int n_in,
                              void* d_out, int out_size, void* d_ws, size_t ws_size,
                              hipStream_t stream) {
  const float* x      = (const float*)d_in[0];
  const float* n1w    = (const float*)d_in[1];
  const float* n1b    = (const float*)d_in[2];
  const float* qkv_w  = (const float*)d_in[3];
  const float* qkv_b  = (const float*)d_in[4];
  const float* proj_w = (const float*)d_in[5];
  const float* proj_b = (const float*)d_in[6];
  const float* rph    = (const float*)d_in[7];
  const float* rpw    = (const float*)d_in[8];
  const float* n2w    = (const float*)d_in[9];
  const float* n2b    = (const float*)d_in[10];
  const float* w1     = (const float*)d_in[11];
  const float* b1     = (const float*)d_in[12];
  const float* w2     = (const float*)d_in[13];
  const float* b2     = (const float*)d_in[14];
  float* out = (float*)d_out;

  char* ws = (char*)d_ws;
  u16* bufT   = (u16*)(ws);             // 38.5 MB: LN1 out -> attn out -> LN2 out
  u16* vTb    = (u16*)(ws + OFF_VT);    // 44.0 MB
  u16* hb     = (u16*)(ws + OFF_H);     // 77.1 MB (aliases vT+; MLP phase only)
  u16* wqkvT  = (u16*)(ws + OFF_W0);
  u16* wprojT = (u16*)(ws + OFF_W1);
  u16* w1T    = (u16*)(ws + OFF_W2);
  u16* w2T    = (u16*)(ws + OFF_W3);
  // q/k live in d_out (dead until PROJ writes x1): 2 x 19,267,584 u16 = 77,070,336 B exact
  u16* qb = (u16*)d_out;
  u16* kb = qb + (size_t)19267584;

  dim3 blk(256);
  transpose_w<<<dim3(72, 24), blk, 0, stream>>>(qkv_w, wqkvT, 768, 2304);
  transpose_w<<<dim3(24, 24), blk, 0, stream>>>(proj_w, wprojT, 768, 768);
  transpose_w<<<dim3(96, 24), blk, 0, stream>>>(w1, w1T, 768, 3072);
  transpose_w<<<dim3(24, 96), blk, 0, stream>>>(w2, w2T, 3072, 768);

  ln_kernel<true><<<6272, blk, 0, stream>>>(x, n1w, n1b, bufT);

  gemm_bt64<EPI_QKV><<<196 * 18, blk, 0, stream>>>(
      bufT, wqkvT, 768, 0, 196, 18, qkv_b, nullptr, qb, kb, vTb, nullptr);

  attn_fused<<<NWH, blk, 0, stream>>>(qb, kb, vTb, rph, rpw, bufT);

  gemm_bt64<EPI_PROJ><<<196 * 6, blk, 0, stream>>>(
      bufT, wprojT, 768, 0, 196, 6, proj_b, x, nullptr, nullptr, nullptr, out);

  ln_kernel<false><<<6272, blk, 0, stream>>>(out, n2w, n2b, bufT);

  for (int c = 0; c < 2; c++) {
    const int row0 = c * 12544;
    gemm_bt64<EPI_MLP1><<<98 * 24, blk, 0, stream>>>(
        bufT + (size_t)row0 * 768, w1T, 768, 0, 98, 24, b1, nullptr, hb, nullptr, nullptr, nullptr);
    gemm_bt64<EPI_MLP2><<<98 * 6, blk, 0, stream>>>(
        hb, w2T, 3072, row0, 98, 6, b2, out, nullptr, nullptr, nullptr, out);
  }

  (void)in_sizes; (void)n_in; (void)out_size; (void)ws_size;
}

// Round 19
// 834.304 us; speedup vs baseline: 1.1901x; 1.0125x over previous
//
#include <hip/hip_runtime.h>
#include <math.h>

typedef unsigned short u16;
typedef __bf16 bf16x8 __attribute__((ext_vector_type(8)));
typedef float   f32x4 __attribute__((ext_vector_type(4)));
typedef u16     u16x4 __attribute__((ext_vector_type(4)));

// ---------- constants ----------
#define TOK 25088      // B*C*H*W
#define EMB 768
#define NWH 1536       // 128 windows * 12 heads
#define NTOKW 196      // tokens per window
#define PROW 224       // padded vT row length (7 * 32) — R7 layout (measured-passing)
#define RELP 228       // rel table row pitch: 114 dwords == 18 mod 32 -> kw*18%32 distinct
                       // for kw 0..13 (was 224: 112 dw == 16 mod 32 -> 2 bank groups,
                       // ~8-way serialize = the measured 4.10M conflicts). 228%4==0: 8B align.
#define PPAD 232       // LDS P-strip row pitch
#define GROUP_M 4      // m-blocks per L2-locality supertile

// workspace byte offsets (q/k live in d_out)
#define OFF_VT 38535168ull
#define OFF_W0 127565824ull           // wqkvT 3,538,944
#define OFF_W1 131104768ull           // wprojT 1,179,648
#define OFF_W2 132284416ull           // w1T 4,718,592
#define OFF_W3 137003008ull           // w2T 4,718,592 -> end 141,721,600
#define OFF_H  38535168ull            // hb aliases vT+ (77,070,336 for 12544 rows)

__device__ __forceinline__ u16 f2bf(float f) {
  __bf16 h = (__bf16)f;
  return __builtin_bit_cast(u16, h);
}

__device__ __forceinline__ float bf2f(u16 u) {
  return __builtin_bit_cast(float, (unsigned)u << 16);
}

__device__ __forceinline__ void cp16(void* lds, const void* gsrc) {
  // async global->LDS, 16B per lane; LDS dest is wave-uniform base (+lane*16 implicit)
  __builtin_amdgcn_global_load_lds((const __attribute__((address_space(1))) void*)gsrc,
                                   (__attribute__((address_space(3))) void*)lds,
                                   16, 0, 0);
}

__device__ __forceinline__ f32x4 mfma16(bf16x8 a, bf16x8 b, f32x4 c) {
  return __builtin_amdgcn_mfma_f32_16x16x32_bf16(a, b, c, 0, 0, 0);
}

// Bijective XCD-chunked block map (m204) composed with GROUP_M supertile.
// Measured (R5): FETCH 97.9->84.6 MB on QKV — keep (no time cost).
__device__ __forceinline__ void map_block(int b, int nwg, int nbm, int nbn,
                                          int* bm, int* bn) {
  const int q = nwg >> 3, r = nwg & 7;
  const int xcd = b & 7, slot = b >> 3;
  const int logical = (xcd < r ? xcd * (q + 1) : r * (q + 1) + (xcd - r) * q) + slot;
  const int in_group = GROUP_M * nbn;
  const int gid = logical / in_group;
  const int rem0 = logical - gid * in_group;
  const int gm = min(GROUP_M, nbm - gid * GROUP_M);   // tail group
  *bm = gid * GROUP_M + rem0 % gm;
  *bn = rem0 / gm;
}

// ---------- weight transpose fp32[R][C] -> bf16[C][R] ----------
__global__ __launch_bounds__(256)
void transpose_w(const float* __restrict__ src, u16* __restrict__ dst, int R, int C) {
  __shared__ float tile[32][33];
  const int tx = threadIdx.x & 31;
  const int ty = threadIdx.x >> 5;
  const int c0 = blockIdx.x * 32;
  const int r0 = blockIdx.y * 32;
  #pragma unroll
  for (int i = ty; i < 32; i += 8)
    tile[i][tx] = src[(size_t)(r0 + i) * C + c0 + tx];
  __syncthreads();
  #pragma unroll
  for (int i = ty; i < 32; i += 8)
    dst[(size_t)(c0 + i) * R + r0 + tx] = f2bf(tile[tx][i]);
}

// ---------- LayerNorm (wave per row) ----------
template<bool WIN>
__global__ __launch_bounds__(256)
void ln_kernel(const float* __restrict__ x, const float* __restrict__ g,
               const float* __restrict__ b, u16* __restrict__ y) {
  const int wave = threadIdx.x >> 6;
  const int lane = threadIdx.x & 63;
  const int row = blockIdx.x * 4 + wave;
  const float* xr = x + (size_t)row * EMB;
  float4 v[3];
  float s = 0.f, ss = 0.f;
  #pragma unroll
  for (int j = 0; j < 3; j++) {
    v[j] = *(const float4*)&xr[lane * 4 + j * 256];
    s  += v[j].x + v[j].y + v[j].z + v[j].w;
    ss += v[j].x*v[j].x + v[j].y*v[j].y + v[j].z*v[j].z + v[j].w*v[j].w;
  }
  #pragma unroll
  for (int off = 1; off < 64; off <<= 1) {
    s  += __shfl_xor(s, off);
    ss += __shfl_xor(ss, off);
  }
  const float mu = s * (1.0f / 768.0f);
  const float var = ss * (1.0f / 768.0f) - mu * mu;
  const float rs = rsqrtf(var + 1e-5f);
  size_t drow;
  if (WIN) {
    const int bc = row / 3136;
    const int rem = row - bc * 3136;
    const int h = rem / 56;
    const int w = rem - h * 56;
    const int window = bc * 16 + (h / 14) * 4 + (w / 14);
    const int token = (h % 14) * 14 + (w % 14);
    drow = (size_t)window * NTOKW + token;
  } else {
    drow = (size_t)row;
  }
  u16* yr = y + drow * EMB;
  #pragma unroll
  for (int j = 0; j < 3; j++) {
    const int e = lane * 4 + j * 256;
    const float4 gv = *(const float4*)&g[e];
    const float4 bv = *(const float4*)&b[e];
    u16x4 o;
    o[0] = f2bf((v[j].x - mu) * rs * gv.x + bv.x);
    o[1] = f2bf((v[j].y - mu) * rs * gv.y + bv.y);
    o[2] = f2bf((v[j].z - mu) * rs * gv.z + bv.z);
    o[3] = f2bf((v[j].w - mu) * rs * gv.w + bv.w);
    *(u16x4*)&yr[e] = o;
  }
}

#define EPI_QKV  0
#define EPI_PROJ 1
#define EPI_MLP1 2
#define EPI_MLP2 3

// ---------- 128x128 bf16 GEMM, BK=64, XOR-swizzled LDS, fused epilogues ----------
// Measured R7: total 955.5 -> 844.7us vs BK=32 structures; GEMMs no longer top-5.
template<int EPI>
__global__ __launch_bounds__(256, 3)
void gemm_bt64(const u16* __restrict__ A, const u16* __restrict__ Bt,
               int K, int moff, int nbm, int nbn,
               const float* __restrict__ bias,
               const float* __restrict__ aux,   // PROJ: x (shortcut); MLP2: x1 (=d_out)
               u16* __restrict__ o0, u16* __restrict__ o1, u16* __restrict__ o2,
               float* of) {
  __shared__ __align__(16) u16 lsA[8192];  // 128 x 64
  __shared__ __align__(16) u16 lsB[8192];
  const int t = threadIdx.x;
  const int wave = t >> 6;
  const int lane = t & 63;
  const int quad = lane >> 4;
  const int l16 = lane & 15;

  int bm, bn;
  map_block(blockIdx.x, gridDim.x, nbm, nbn, &bm, &bn);
  const int m0 = bm * 128;
  const int n0 = bn * 128;

  const int wm = (wave >> 1) * 64;
  const int wn = (wave & 1) * 64;

  // staging: chunk c = issue*256 + t; row = 32*issue + (t>>3); phys chunk = t&7;
  // logical col chunk = (t ^ (t>>3)) & 7  (issue-independent since 32*issue%8==0)
  const int sr = t >> 3;
  const int sc = ((t ^ (t >> 3)) & 7) * 8;
  const u16* Ag = A + (size_t)(m0 + sr) * K + sc;
  const u16* Bg = Bt + (size_t)(n0 + sr) * K + sc;
  u16* dA = lsA + wave * 512;
  u16* dB = lsB + wave * 512;

  // ds_read swizzled chunk offsets (row&7 == l16&7: row bases are multiples of 16)
  const int cK0 = ((quad    ) ^ (l16 & 7)) * 8;
  const int cK1 = ((4 + quad) ^ (l16 & 7)) * 8;

  f32x4 acc[4][4];
  const f32x4 zero4 = {0.f, 0.f, 0.f, 0.f};
  #pragma unroll
  for (int i = 0; i < 4; i++)
    #pragma unroll
    for (int j = 0; j < 4; j++) acc[i][j] = zero4;

  for (int k0 = 0; k0 < K; k0 += 64) {
    #pragma unroll
    for (int i = 0; i < 4; i++) {
      cp16(dA + i * 2048, Ag + (size_t)(32 * i) * K + k0);
      cp16(dB + i * 2048, Bg + (size_t)(32 * i) * K + k0);
    }
    __syncthreads();           // drains vmcnt for global_load_lds
    #pragma unroll
    for (int ks = 0; ks < 2; ks++) {
      const int kc = ks ? cK1 : cK0;
      bf16x8 af[4], bfr[4];
      #pragma unroll
      for (int i = 0; i < 4; i++)
        af[i] = *(const bf16x8*)&lsA[(wm + i * 16 + l16) * 64 + kc];
      #pragma unroll
      for (int j = 0; j < 4; j++)
        bfr[j] = *(const bf16x8*)&lsB[(wn + j * 16 + l16) * 64 + kc];
      #pragma unroll
      for (int i = 0; i < 4; i++)
        #pragma unroll
        for (int j = 0; j < 4; j++)
          acc[i][j] = mfma16(af[i], bfr[j], acc[i][j]);
    }
    __syncthreads();
  }

  // epilogue: lane holds D[row = quad*4+r][col = l16] per 16x16 tile
  #pragma unroll
  for (int i = 0; i < 4; i++) {
    const int mb = m0 + wm + i * 16 + quad * 4;
    #pragma unroll
    for (int j = 0; j < 4; j++) {
      const int n = n0 + wn + j * 16 + l16;
      const float bn_ = bias[n];
      if (EPI == EPI_QKV) {
        const int j3 = n / 768;
        const int rem = n - j3 * 768;
        const int head = rem >> 6;
        const int d = rem & 63;
        if (j3 == 2) {
          // v stored transposed: vT[wh][d][PROW], 4 consecutive tokens per lane
          const int window = mb / 196;
          const int token = mb - window * 196;   // mb%4==0, 196%4==0 -> same window
          const int wh = window * 12 + head;
          u16x4 pv;
          #pragma unroll
          for (int r = 0; r < 4; r++) pv[r] = f2bf(acc[i][j][r] + bn_);
          *(u16x4*)&o2[((size_t)wh * 64 + d) * PROW + token] = pv;
        } else {
          u16* dst = (j3 == 0) ? o0 : o1;
          #pragma unroll
          for (int r = 0; r < 4; r++) {
            const int m = mb + r;
            const int window = m / 196;
            const int token = m - window * 196;
            const int wh = window * 12 + head;
            dst[((size_t)wh * NTOKW + token) * 64 + d] = f2bf(acc[i][j][r] + bn_);
          }
        }
      } else if (EPI == EPI_PROJ) {
        #pragma unroll
        for (int r = 0; r < 4; r++) {
          const int m = mb + r;
          const int window = m / 196;
          const int token = m - window * 196;
          const int bc = window >> 4;
          const int wi = window & 15;
          const int th = token / 14;
          const int tw = token - th * 14;
          const int h = (wi >> 2) * 14 + th;
          const int w = (wi & 3) * 14 + tw;
          const size_t flat = (((size_t)bc * 56 + h) * 56 + w) * 768 + n;
          of[flat] = acc[i][j][r] + bn_ + aux[flat];   // x1 = proj + bias + shortcut
        }
      } else if (EPI == EPI_MLP1) {
        #pragma unroll
        for (int r = 0; r < 4; r++) {
          const int m = mb + r;
          float v = acc[i][j][r] + bn_;
          v = 0.5f * v * (1.0f + erff(v * 0.70710678118654752f));  // exact GELU
          o0[(size_t)m * 3072 + n] = f2bf(v);
        }
      } else {  // EPI_MLP2
        #pragma unroll
        for (int r = 0; r < 4; r++) {
          const int m = mb + r + moff;
          const size_t idx = (size_t)m * 768 + n;
          of[idx] = acc[i][j][r] + bn_ + aux[idx];     // out = z + x1
        }
      }
    }
  }
}

// ---------- fused attention: S=scale*qk^T+rel, softmax, O=P@V — one kernel ----------
// lsK XOR-swizzled: physical chunk c of row holds logical c^(row&7) (8 chunks/row).
// R15: R7-exact structure (measured-passing 844.7us); sole change = RELP=228 rel pitch.
// vT2 chunked layout QUARANTINED: R12 failed post-timing with a mechanism that
// contradicts the stale-tail theory (R7 has identical stale exposure and passes).
__global__ __launch_bounds__(256, 2)
void attn_fused(const u16* __restrict__ q, const u16* __restrict__ k,
                const u16* __restrict__ vT,
                const float* __restrict__ rph, const float* __restrict__ rpw,
                u16* __restrict__ out) {
  __shared__ __align__(16) u16 lsK[208 * 64];     // 26624 B (rows 196.. stale; cols masked)
  __shared__ __align__(16) u16 relh[16 * RELP];   // bf16 [kh][i]  7296 B
  __shared__ __align__(16) u16 relw[16 * RELP];   // bf16 [kw][i]  7296 B
  __shared__ __align__(16) u16 lsP[4][16 * PPAD]; // 29696 B, wave-private strips
  const int t = threadIdx.x;
  const int wave = t >> 6;
  const int lane = t & 63;
  const int quad = lane >> 4;
  const int l16 = lane & 15;
  const int wh = blockIdx.x;
  const u16* qg = q + (size_t)wh * (NTOKW * 64);
  const u16* kg = k + (size_t)wh * (NTOKW * 64);
  const u16* vg = vT + (size_t)wh * 64 * PROW;
  const int window = wh / 12;
  const int head = wh - window * 12;

  // stage k rows 0..195 with XOR source swizzle (chunk c of row r <- logical c^(r&7))
  #pragma unroll
  for (int i = 0; i < 6; i++) {
    const int chunk = i * 256 + t;
    const int goff = ((chunk & ~7) | ((chunk ^ (chunk >> 3)) & 7)) * 8;
    cp16(lsK + (i * 256 + wave * 64) * 8, kg + goff);
  }
  if (t < 32) {
    const int chunk = 1536 + t;
    const int goff = ((chunk & ~7) | ((chunk ^ (chunk >> 3)) & 7)) * 8;
    cp16(lsK + 1536 * 8, kg + goff);
  }

  // rel_h / rel_w tables via MFMA (bf16 in LDS)
  const f32x4 zero4 = {0.f, 0.f, 0.f, 0.f};
  for (int tile = wave; tile < 14; tile += 4) {
    f32x4 ah = zero4, aw = zero4;
    const int ridx = min(max(tile - l16 + 13, 0), 26);  // clamp (l16>=14 cols discarded)
    #pragma unroll
    for (int ks = 0; ks < 2; ks++) {
      const int ko = ks * 32 + quad * 8;
      bf16x8 aq_h = *(const bf16x8*)&qg[(tile * 14 + l16) * 64 + ko];
      bf16x8 aq_w = *(const bf16x8*)&qg[(tile + 14 * l16) * 64 + ko];
      bf16x8 bh, bw;
      const float* ph = rph + ridx * 64 + ko;
      const float* pw = rpw + ridx * 64 + ko;
      #pragma unroll
      for (int e = 0; e < 8; e++) { bh[e] = (__bf16)ph[e]; bw[e] = (__bf16)pw[e]; }
      ah = mfma16(aq_h, bh, ah);
      aw = mfma16(aq_w, bw, aw);
    }
    #pragma unroll
    for (int r = 0; r < 4; r++) {
      const int m = quad * 4 + r;
      if (m < 14) {
        relh[l16 * RELP + tile * 14 + m] = f2bf(ah[r]);
        relw[l16 * RELP + tile + 14 * m] = f2bf(aw[r]);
      }
    }
  }
  __syncthreads();   // drains cp16 vmcnt + publishes rel tables

  const float scale = 0.125f;  // 64^-0.5
  const int sw = l16 & 7;      // lsK read swizzle (row&7 == l16&7 for rows = jt*16+l16)
  u16* myP = &lsP[wave][0];
  for (int s = wave; s < 13; s += 4) {
    bf16x8 aq[2];
    #pragma unroll
    for (int ks = 0; ks < 2; ks++)
      aq[ks] = *(const bf16x8*)&qg[(s * 16 + l16) * 64 + ks * 32 + quad * 8];
    f32x4 acc[13];
    #pragma unroll
    for (int jt = 0; jt < 13; jt++) {
      f32x4 a = zero4;
      a = mfma16(aq[0], *(const bf16x8*)&lsK[(jt * 16 + l16) * 64 + (quad ^ sw) * 8], a);
      a = mfma16(aq[1], *(const bf16x8*)&lsK[(jt * 16 + l16) * 64 + ((quad + 4) ^ sw) * 8], a);
      acc[jt] = a;
    }
    f32x4 mx = {-1e30f, -1e30f, -1e30f, -1e30f};
    #pragma unroll
    for (int jt = 0; jt < 13; jt++) {
      const int col = jt * 16 + l16;
      if (col < 196) {
        const int kh = col / 14;
        const int kw = col - kh * 14;
        const u16x4 rhu = *(const u16x4*)&relh[kh * RELP + s * 16 + quad * 4];
        const u16x4 rwu = *(const u16x4*)&relw[kw * RELP + s * 16 + quad * 4];
        #pragma unroll
        for (int r = 0; r < 4; r++)
          acc[jt][r] = acc[jt][r] * scale + bf2f(rhu[r]) + bf2f(rwu[r]);
      } else {
        acc[jt] = (f32x4){-1e30f, -1e30f, -1e30f, -1e30f};  // full overwrite: kills stale LDS
      }
      #pragma unroll
      for (int r = 0; r < 4; r++) mx[r] = fmaxf(mx[r], acc[jt][r]);
    }
    // rows live per-quad (xor masks <16 stay inside the 16-lane group)
    #pragma unroll
    for (int off = 1; off < 16; off <<= 1)
      #pragma unroll
      for (int r = 0; r < 4; r++) mx[r] = fmaxf(mx[r], __shfl_xor(mx[r], off));
    f32x4 sum = zero4;
    #pragma unroll
    for (int jt = 0; jt < 13; jt++)
      #pragma unroll
      for (int r = 0; r < 4; r++) {
        const float p = exp2f((acc[jt][r] - mx[r]) * 1.4426950408889634f);
        acc[jt][r] = p;
        sum[r] += p;
      }
    #pragma unroll
    for (int off = 1; off < 16; off <<= 1)
      #pragma unroll
      for (int r = 0; r < 4; r++) sum[r] += __shfl_xor(sum[r], off);
    // write P strip (wave-private; rows = quad*4+r, cols = jt*16+l16)
    #pragma unroll
    for (int r = 0; r < 4; r++) {
      const float rinv = 1.0f / sum[r];
      const int prow = (quad * 4 + r) * PPAD;
      #pragma unroll
      for (int jt = 0; jt < 13; jt++)
        myP[prow + jt * 16 + l16] = f2bf(acc[jt][r] * rinv);
      myP[prow + 208 + l16] = 0;   // zero pad cols 208..223
    }
    asm volatile("s_waitcnt lgkmcnt(0)" ::: "memory");  // P strip visible to own wave
    // O = P @ V ; A-frag from LDS strip, B-frag (vT) from global (L1/L2-resident)
    f32x4 acco[4] = {zero4, zero4, zero4, zero4};
    #pragma unroll
    for (int ks = 0; ks < 7; ks++) {
      bf16x8 ap = *(const bf16x8*)&myP[l16 * PPAD + ks * 32 + quad * 8];
      #pragma unroll
      for (int nt = 0; nt < 4; nt++) {
        bf16x8 bv = *(const bf16x8*)&vg[(nt * 16 + l16) * PROW + ks * 32 + quad * 8];
        acco[nt] = mfma16(ap, bv, acco[nt]);
      }
    }
    #pragma unroll
    for (int nt = 0; nt < 4; nt++)
      #pragma unroll
      for (int r = 0; r < 4; r++) {
        const int i = s * 16 + quad * 4 + r;
        if (i < 196)
          out[((size_t)window * NTOKW + i) * EMB + head * 64 + nt * 16 + l16] =
              f2bf(acco[nt][r]);
      }
  }
}

// ---------- launch ----------
extern "C" void kernel_launch(void* const* d_in, const int* in_sizes, int n_in,
                              void* d_out, int out_size, void* d_ws, size_t ws_size,
                              hipStream_t stream) {
  const float* x      = (const float*)d_in[0];
  const float* n1w    = (const float*)d_in[1];
  const float* n1b    = (const float*)d_in[2];
  const float* qkv_w  = (const float*)d_in[3];
  const float* qkv_b  = (const float*)d_in[4];
  const float* proj_w = (const float*)d_in[5];
  const float* proj_b = (const float*)d_in[6];
  const float* rph    = (const float*)d_in[7];
  const float* rpw    = (const float*)d_in[8];
  const float* n2w    = (const float*)d_in[9];
  const float* n2b    = (const float*)d_in[10];
  const float* w1     = (const float*)d_in[11];
  const float* b1     = (const float*)d_in[12];
  const float* w2     = (const float*)d_in[13];
  const float* b2     = (const float*)d_in[14];
  float* out = (float*)d_out;

  char* ws = (char*)d_ws;
  u16* bufT   = (u16*)(ws);             // 38.5 MB: LN1 out -> attn out -> LN2 out
  u16* vTb    = (u16*)(ws + OFF_VT);    // 44.0 MB
  u16* hb     = (u16*)(ws + OFF_H);     // 77.1 MB (aliases vT+; MLP phase only)
  u16* wqkvT  = (u16*)(ws + OFF_W0);
  u16* wprojT = (u16*)(ws + OFF_W1);
  u16* w1T    = (u16*)(ws + OFF_W2);
  u16* w2T    = (u16*)(ws + OFF_W3);
  // q/k live in d_out (dead until PROJ writes x1): 2 x 19,267,584 u16 = 77,070,336 B exact
  u16* qb = (u16*)d_out;
  u16* kb = qb + (size_t)19267584;

  dim3 blk(256);
  transpose_w<<<dim3(72, 24), blk, 0, stream>>>(qkv_w, wqkvT, 768, 2304);
  transpose_w<<<dim3(24, 24), blk, 0, stream>>>(proj_w, wprojT, 768, 768);
  transpose_w<<<dim3(96, 24), blk, 0, stream>>>(w1, w1T, 768, 3072);
  transpose_w<<<dim3(24, 96), blk, 0, stream>>>(w2, w2T, 3072, 768);

  ln_kernel<true><<<6272, blk, 0, stream>>>(x, n1w, n1b, bufT);

  gemm_bt64<EPI_QKV><<<196 * 18, blk, 0, stream>>>(
      bufT, wqkvT, 768, 0, 196, 18, qkv_b, nullptr, qb, kb, vTb, nullptr);

  attn_fused<<<NWH, blk, 0, stream>>>(qb, kb, vTb, rph, rpw, bufT);

  gemm_bt64<EPI_PROJ><<<196 * 6, blk, 0, stream>>>(
      bufT, wprojT, 768, 0, 196, 6, proj_b, x, nullptr, nullptr, nullptr, out);

  ln_kernel<false><<<6272, blk, 0, stream>>>(out, n2w, n2b, bufT);

  for (int c = 0; c < 2; c++) {
    const int row0 = c * 12544;
    gemm_bt64<EPI_MLP1><<<98 * 24, blk, 0, stream>>>(
        bufT + (size_t)row0 * 768, w1T, 768, 0, 98, 24, b1, nullptr, hb, nullptr, nullptr, nullptr);
    gemm_bt64<EPI_MLP2><<<98 * 6, blk, 0, stream>>>(
        hb, w2T, 3072, row0, 98, 6, b2, out, nullptr, nullptr, nullptr, out);
  }

  (void)in_sizes; (void)n_in; (void)out_size; (void)ws_size;
}